// Round 7
// baseline (310.710 us; speedup 1.0000x reference)
//
#include <hip/hip_runtime.h>
#include <cstddef>

#define HH 720
#define WW 1280
#define FRAME 1843200            // 2*720*1280
#define FRAME4 460800            // FRAME/4
#define T_EVT 10
#define T_TOTAL 20
#define ARRIVE64 (1ULL << 32)

// ---------- old (fallback) path config ----------
#define ONBLK 256
#define ONTHR 1024
#define ONWPB 16
#define ONT (ONBLK * ONTHR)

// ---------- new path config ----------
#define SBLK 1024                // scan blocks (4 per CU)
#define STHR 256                 // scan threads per block (4 waves)
#define SWPB 4
#define PIXB 1800                // pixels per scan block
#define NGROUP4 450              // float4 groups per block (1800/4)
#define HIST_W 9000              // LDS hist words (18000 u16)
#define RBLK 512                 // passA/passB blocks / mat rows
#define RTHR 1024
#define NBUCKET 1024
#define EPT 8                    // records/thread (8*1024=8192 >= chunk4)
#define MAXM (EPT * RTHR)
#define OBLK 16
#define OROWG 16                 // row groups (threads >> 6)
#define OROWS 32                 // rows per thread (512/16)

// ws layout (bytes), all 256-aligned
#define MAT_OFF   0u                           // u32[512*1024] = 2 MB
#define CS_OFF    (512u * 1024u * 4u)          // u32[1024] column sums
#define SB_OFF    (CS_OFF + 4096u)             // u32[1025] seg bases
#define KEY_OFF   (SB_OFF + 8192u)             // u32[n] pix keys
#define SEG_OFF(n) (KEY_OFF + 4u * (unsigned)(n))        // u16[n]
#define WS_NEED(n) ((size_t)SEG_OFF(n) + 2ull * (size_t)(n) + 256ull)

// Persistent device globals.
__device__ unsigned g_minkey;
__device__ unsigned g_maxkey;
// per-block minmax partials (plain stores; fully overwritten by passA's 512
// blocks each run, reduced by offsets block 0). Cross-kernel visibility via
// kernel boundaries only (R18 lesson: in-kernel cross-block plain-store
// handoff failed correctness; kernel-boundary sync is the proven mechanism).
__device__ unsigned g_part_mn[RBLK];
__device__ unsigned g_part_mx[RBLK];
// old-path tree (R8, proven)
__device__ unsigned long long g_grp[T_TOTAL][16][16];
__device__ unsigned long long g_top[T_TOTAL][16];
__device__ unsigned g_rel[T_TOTAL][32];
// scan_new tree: 1024 -> 64 -> 4 -> 1, fan-out to 64 group-release words
__device__ unsigned long long g_n1[T_TOTAL][64][16];
__device__ unsigned long long g_n2[T_TOTAL][4][16];
__device__ unsigned long long g_n3[T_TOTAL][16];
__device__ unsigned g_relg[T_TOTAL][64][32];   // [s][group][0]: total+1

__device__ __forceinline__ unsigned f2key(float f) {
    unsigned b = __float_as_uint(f);
    return b ^ ((unsigned)(((int)b) >> 31) | 0x80000000u);
}
__device__ __forceinline__ float key2f(unsigned k) {
    unsigned b = (k & 0x80000000u) ? (k ^ 0x80000000u) : ~k;
    return __uint_as_float(b);
}

// Exact reference bin: ((t-tmin)/(tmax-tmin))*(10-1e-6), trunc, clip.
__device__ __forceinline__ int event_bin_t(float tv, float tmin, float tmax) {
#pragma clang fp contract(off)
    float tn;
    if (tmax > tmin) tn = (tv - tmin) / (tmax - tmin) * (float)(10.0 - 1e-6);
    else tn = 0.0f;
    int ti = (int)tn;
    return ti < 0 ? 0 : (ti > T_EVT - 1 ? T_EVT - 1 : ti);
}
__device__ __forceinline__ int event_pixel(int xi, int yi, int ci) {
    xi = xi < 0 ? 0 : (xi > WW - 1 ? WW - 1 : xi);
    yi = yi < 0 ? 0 : (yi > HH - 1 ? HH - 1 : yi);
    return ci * (HH * WW) + yi * WW + xi;
}

// init_kernel: FALLBACK PATH ONLY.
__global__ void init_kernel() {
    const int gtid = blockIdx.x * blockDim.x + threadIdx.x;
    const int gs = gridDim.x * blockDim.x;
    if (gtid == 0) { g_minkey = 0xFFFFFFFFu; g_maxkey = 0u; }
    unsigned long long* a = &g_grp[0][0][0];
    for (int i = gtid; i < T_TOTAL * 16 * 16; i += gs) a[i] = 0ull;
    unsigned long long* b = &g_top[0][0];
    for (int i = gtid; i < T_TOTAL * 16; i += gs) b[i] = 0ull;
    unsigned* c = &g_rel[0][0];
    for (int i = gtid; i < T_TOTAL * 32; i += gs) c[i] = 0u;
}

// ======================= shared: t min/max (fallback path) ==============
__device__ __forceinline__ void minmax_body(const float* __restrict__ t, int n,
                                            int gtid, int gstride) {
    unsigned mn = 0xFFFFFFFFu, mx = 0u;
    const int n4 = n >> 2;
    const float4* t4 = (const float4*)t;
    for (int i = gtid; i < n4; i += gstride) {
        float4 tv = t4[i];
        unsigned k0 = f2key(tv.x), k1 = f2key(tv.y);
        unsigned k2 = f2key(tv.z), k3 = f2key(tv.w);
        unsigned a = k0 < k1 ? k0 : k1, b = k2 < k3 ? k2 : k3;
        unsigned c = a < b ? a : b;
        mn = mn < c ? mn : c;
        a = k0 > k1 ? k0 : k1; b = k2 > k3 ? k2 : k3;
        c = a > b ? a : b;
        mx = mx > c ? mx : c;
    }
    for (int i = (n4 << 2) + gtid; i < n; i += gstride) {
        unsigned k = f2key(t[i]);
        mn = mn < k ? mn : k;
        mx = mx > k ? mx : k;
    }
    for (int off = 32; off > 0; off >>= 1) {
        unsigned omn = (unsigned)__shfl_down((int)mn, off, 64);
        unsigned omx = (unsigned)__shfl_down((int)mx, off, 64);
        mn = mn < omn ? mn : omn;
        mx = mx > omx ? mx : omx;
    }
    __shared__ unsigned smn[16], smx[16];
    int lane = threadIdx.x & 63, wv = threadIdx.x >> 6;
    if (lane == 0) { smn[wv] = mn; smx[wv] = mx; }
    __syncthreads();
    if (threadIdx.x == 0) {
        int nw = blockDim.x >> 6;
        for (int i = 1; i < nw; ++i) {
            mn = mn < smn[i] ? mn : smn[i];
            mx = mx > smx[i] ? mx : smx[i];
        }
        atomicMin(&g_minkey, mn);
        atomicMax(&g_maxkey, mx);
    }
}

__global__ void minmax_zero_kernel(const float* __restrict__ t, int n,
                                   uint4* __restrict__ hist16v) {
    const int gtid = blockIdx.x * blockDim.x + threadIdx.x;
    const int gstride = gridDim.x * blockDim.x;
    const uint4 z = make_uint4(0u, 0u, 0u, 0u);
    const int nz = T_EVT * FRAME / 8;
    for (int i = gtid; i < nz; i += gstride) hist16v[i] = z;
    minmax_body(t, n, gtid, gstride);
}

// ======================= new path: counting sort =======================
// passA (R19): 4-wide vectorized event loop. Chunk rounded to a multiple of
// 4 (7816) so int4/float4 loads are legal and 16B-aligned (s0*4 % 16 == 0).
// Each thread handles 4 consecutive events per iteration: 4x fewer load
// instructions and address calcs on the 64 MB input stream; keys written
// as int4. Bucket multiset per block and minmax set are bit-identical.
__global__ __launch_bounds__(RTHR) void passA_kernel(
        const int* __restrict__ x, const int* __restrict__ y,
        const int* __restrict__ p, const float* __restrict__ t,
        unsigned* __restrict__ mat, unsigned* __restrict__ keys, int n) {
    __shared__ unsigned cnt[NBUCKET];
    const int gtid = blockIdx.x * blockDim.x + threadIdx.x;
    const int gs = gridDim.x * blockDim.x;
    {   // zero scan_new's sync tree (kernel boundary = visibility for scan)
        unsigned long long* z1 = &g_n1[0][0][0];
        for (int i = gtid; i < T_TOTAL * 64 * 16; i += gs) z1[i] = 0ull;
        unsigned long long* z2 = &g_n2[0][0][0];
        for (int i = gtid; i < T_TOTAL * 4 * 16; i += gs) z2[i] = 0ull;
        unsigned long long* z3 = &g_n3[0][0];
        for (int i = gtid; i < T_TOTAL * 16; i += gs) z3[i] = 0ull;
        unsigned* z4 = &g_relg[0][0][0];
        for (int i = gtid; i < T_TOTAL * 64 * 32; i += gs) z4[i] = 0u;
    }
    for (int i = threadIdx.x; i < NBUCKET; i += blockDim.x) cnt[i] = 0u;
    __syncthreads();
    const int chunk = (((n + RBLK - 1) / RBLK) + 3) & ~3;   // mult of 4
    const int s0 = blockIdx.x * chunk;
    const int s1 = min(n, s0 + chunk);
    unsigned mn = 0xFFFFFFFFu, mx = 0u;
    for (int base = s0 + (threadIdx.x << 2); base < s1; base += (RTHR << 2)) {
        if (base + 4 <= s1) {
            int4 xv = *(const int4*)(x + base);
            int4 yv = *(const int4*)(y + base);
            int4 pv = *(const int4*)(p + base);
            float4 tv = *(const float4*)(t + base);
            int p0 = event_pixel(xv.x, yv.x, pv.x);
            int p1 = event_pixel(xv.y, yv.y, pv.y);
            int p2 = event_pixel(xv.z, yv.z, pv.z);
            int p3 = event_pixel(xv.w, yv.w, pv.w);
            *(int4*)(keys + base) = make_int4(p0, p1, p2, p3);
            atomicAdd(&cnt[p0 / PIXB], 1u);
            atomicAdd(&cnt[p1 / PIXB], 1u);
            atomicAdd(&cnt[p2 / PIXB], 1u);
            atomicAdd(&cnt[p3 / PIXB], 1u);
            unsigned k0 = f2key(tv.x), k1 = f2key(tv.y);
            unsigned k2 = f2key(tv.z), k3 = f2key(tv.w);
            unsigned a = k0 < k1 ? k0 : k1, b = k2 < k3 ? k2 : k3;
            unsigned c = a < b ? a : b;
            mn = mn < c ? mn : c;
            a = k0 > k1 ? k0 : k1; b = k2 > k3 ? k2 : k3;
            c = a > b ? a : b;
            mx = mx > c ? mx : c;
        } else {
            for (int e = 0; e < 4; ++e) {
                int i = base + e;
                if (i < s1) {
                    int pix = event_pixel(x[i], y[i], p[i]);
                    keys[i] = (unsigned)pix;
                    atomicAdd(&cnt[pix / PIXB], 1u);
                    unsigned k = f2key(t[i]);
                    mn = mn < k ? mn : k;
                    mx = mx > k ? mx : k;
                }
            }
        }
    }
    // block minmax reduce -> per-block partial (plain store)
    for (int off = 32; off > 0; off >>= 1) {
        unsigned omn = (unsigned)__shfl_down((int)mn, off, 64);
        unsigned omx = (unsigned)__shfl_down((int)mx, off, 64);
        mn = mn < omn ? mn : omn;
        mx = mx > omx ? mx : omx;
    }
    __shared__ unsigned smn[RTHR / 64], smx[RTHR / 64];
    const int lane = threadIdx.x & 63, wv = threadIdx.x >> 6;
    if (lane == 0) { smn[wv] = mn; smx[wv] = mx; }
    __syncthreads();
    if (threadIdx.x == 0) {
#pragma unroll
        for (int i = 1; i < RTHR / 64; ++i) {
            mn = mn < smn[i] ? mn : smn[i];
            mx = mx > smx[i] ? mx : smx[i];
        }
        g_part_mn[blockIdx.x] = mn;
        g_part_mx[blockIdx.x] = mx;
    }
    for (int i = threadIdx.x; i < NBUCKET; i += blockDim.x)
        mat[blockIdx.x * NBUCKET + i] = cnt[i];
}

// offsets v2 (R17, proven): 16 blocks x 1024 thr; block owns 64 CONSECUTIVE
// bucket columns; coalesced two-pass column scan. Block 0 also reduces the
// 512 minmax partials -> g_minkey/g_maxkey.
__global__ __launch_bounds__(1024) void offsets_kernel(
        unsigned* __restrict__ mat, unsigned* __restrict__ colsum) {
    const int t = threadIdx.x;
    const int c = t & 63;            // column within block's group
    const int rg = t >> 6;           // row group 0..15
    const int j = blockIdx.x * 64 + c;
    __shared__ unsigned part[OROWG][64];
    unsigned sum = 0u;
    for (int k = 0; k < OROWS; ++k)
        sum += mat[(rg * OROWS + k) * NBUCKET + j];
    part[rg][c] = sum;
    __syncthreads();
    if (rg == 0) {                   // thread c: serial scan of 16 partials
        unsigned run = 0u;
#pragma unroll
        for (int g = 0; g < OROWG; ++g) {
            unsigned v = part[g][c];
            part[g][c] = run;
            run += v;
        }
        colsum[j] = run;             // inclusive total of column j
    }
    __syncthreads();
    unsigned running = part[rg][c];
    for (int k = 0; k < OROWS; ++k) {
        const int idx = (rg * OROWS + k) * NBUCKET + j;
        unsigned v = mat[idx];
        mat[idx] = running;          // exclusive prefix within column
        running += v;
    }

    if (blockIdx.x == 0) {           // minmax partial reduce (512 partials)
        const int lane = t & 63, wv = t >> 6;
        unsigned mn = 0xFFFFFFFFu, mx = 0u;
        if (t < RBLK) { mn = g_part_mn[t]; mx = g_part_mx[t]; }
        for (int off = 32; off > 0; off >>= 1) {
            unsigned omn = (unsigned)__shfl_down((int)mn, off, 64);
            unsigned omx = (unsigned)__shfl_down((int)mx, off, 64);
            mn = mn < omn ? mn : omn;
            mx = mx > omx ? mx : omx;
        }
        __shared__ unsigned smn2[16], smx2[16];
        if (lane == 0) { smn2[wv] = mn; smx2[wv] = mx; }
        __syncthreads();
        if (t == 0) {
#pragma unroll
            for (int k = 1; k < 16; ++k) {
                mn = mn < smn2[k] ? mn : smn2[k];
                mx = mx > smx2[k] ? mx : smx2[k];
            }
            g_minkey = mn;
            g_maxkey = mx;
        }
    }
}

// passB (R19): R17 v3 structure with 4-wide vectorized phase-1 reads
// (uint4 keys + float4 t, same chunk4 partition as passA). 512 blocks, one
// chunk each, 40 KB LDS -> 2 blocks/CU. LDS counting sort + coalesced flush.
__global__ __launch_bounds__(RTHR) void passB_kernel(
        const unsigned* __restrict__ keys, const float* __restrict__ t,
        const unsigned* __restrict__ mat, const unsigned* __restrict__ colsum,
        unsigned* __restrict__ seg_base_out,
        unsigned short* __restrict__ seg, int n) {
    __shared__ unsigned base[NBUCKET];   // global run start -> gdst
    __shared__ unsigned lrun[NBUCKET];   // local count -> excl scan -> rank
    __shared__ unsigned wt2[RTHR / 64];
    __shared__ unsigned short sorted[MAXM];  // 16 KB
    __shared__ unsigned short sbkt[MAXM];    // 16 KB
    const int j = threadIdx.x;           // RTHR == NBUCKET
    const int lane = j & 63, wv = j >> 6;
    {   // prologue: global exclusive scan of colsum; base = mat[bid][j]+ex
        unsigned v = colsum[j];
        unsigned incl = v;
        for (int off = 1; off < 64; off <<= 1) {
            unsigned o = (unsigned)__shfl_up((int)incl, off, 64);
            if (lane >= off) incl += o;
        }
        if (lane == 63) wt2[wv] = incl;
        __syncthreads();
        if (j == 0) {
            unsigned run = 0;
#pragma unroll
            for (int k = 0; k < RTHR / 64; ++k) { unsigned tmp = wt2[k]; wt2[k] = run; run += tmp; }
        }
        __syncthreads();
        unsigned ex = incl - v + wt2[wv];
        base[j] = mat[blockIdx.x * NBUCKET + j] + ex;
        lrun[j] = 0u;
        if (blockIdx.x == 0) {
            seg_base_out[j] = ex;
            if (j == NBUCKET - 1) seg_base_out[NBUCKET] = ex + v;
        }
    }
    __syncthreads();
    const float tmin = key2f(g_minkey);
    const float tmax = key2f(g_maxkey);
    const int chunk = (((n + RBLK - 1) / RBLK) + 3) & ~3;   // mult of 4
    const int s0 = blockIdx.x * chunk;
    const int s1 = min(n, s0 + chunk);
    const int m = s1 - s0;               // <= MAXM (launcher-guarded)

    // phase 1: vectorized read, records in registers, count buckets.
    // i = s0 + (k*RTHR + j)*4 + e covers [s0, s0+8192) uniquely.
    unsigned rec[EPT];
#pragma unroll
    for (int k = 0; k < EPT / 4; ++k) {
        const int ibase = s0 + ((k * RTHR + j) << 2);
#pragma unroll
        for (int e = 0; e < 4; ++e) rec[k * 4 + e] = 0xFFFFFFFFu;
        if (ibase + 4 <= s1) {
            uint4 kv = *(const uint4*)(keys + ibase);
            float4 tv = *(const float4*)(t + ibase);
            unsigned pxs[4] = { kv.x, kv.y, kv.z, kv.w };
            float ts[4] = { tv.x, tv.y, tv.z, tv.w };
#pragma unroll
            for (int e = 0; e < 4; ++e) {
                int pix = (int)pxs[e];
                int ti = event_bin_t(ts[e], tmin, tmax);
                int bkt = pix / PIXB;
                int lb = ti * PIXB + (pix - bkt * PIXB);   // < 18000
                rec[k * 4 + e] = ((unsigned)bkt << 16) | (unsigned)lb;
                atomicAdd(&lrun[bkt], 1u);
            }
        } else if (ibase < s1) {
            for (int e = 0; e < 4; ++e) {
                int i = ibase + e;
                if (i < s1) {
                    int pix = (int)keys[i];
                    int ti = event_bin_t(t[i], tmin, tmax);
                    int bkt = pix / PIXB;
                    int lb = ti * PIXB + (pix - bkt * PIXB);
                    rec[k * 4 + e] = ((unsigned)bkt << 16) | (unsigned)lb;
                    atomicAdd(&lrun[bkt], 1u);
                }
            }
        }
    }
    __syncthreads();
    // phase 2: block scan lrun -> exclusive offsets; gdst = base - lofs
    {
        unsigned v = lrun[j];
        unsigned incl = v;
        for (int off = 1; off < 64; off <<= 1) {
            unsigned o = (unsigned)__shfl_up((int)incl, off, 64);
            if (lane >= off) incl += o;
        }
        if (lane == 63) wt2[wv] = incl;
        __syncthreads();
        if (j == 0) {
            unsigned run = 0;
#pragma unroll
            for (int k = 0; k < RTHR / 64; ++k) { unsigned tmp = wt2[k]; wt2[k] = run; run += tmp; }
        }
        __syncthreads();
        unsigned ex = incl - v + wt2[wv];
        base[j] -= ex;       // gdst[j]: global dst = gdst[j] + local sorted idx
        lrun[j] = ex;        // running rank counter, seeded with excl scan
    }
    __syncthreads();
    // phase 3: rank from registers -> LDS sorted array
#pragma unroll
    for (int k = 0; k < EPT; ++k) {
        unsigned r0 = rec[k];
        if (r0 != 0xFFFFFFFFu) {
            unsigned bkt = r0 >> 16;
            unsigned r = atomicAdd(&lrun[bkt], 1u);
            sorted[r] = (unsigned short)(r0 & 0xFFFFu);
            sbkt[r] = (unsigned short)bkt;
        }
    }
    __syncthreads();
    // phase 4: coalesced flush (consecutive i in a bucket -> consec dst)
    for (int i = j; i < m; i += RTHR) {
        unsigned bk = sbkt[i];
        seg[base[bk] + (unsigned)i] = sorted[i];
    }
}

// Cooperative scan, 1024 blocks x 256 thr, 36 KB LDS hist (R9-R17, proven,
// byte-identical to the 309 us version).
__global__ __launch_bounds__(STHR, 4) void scan_new(float* __restrict__ out,
                                                    const unsigned short* __restrict__ seg,
                                                    const unsigned* __restrict__ seg_base) {
#pragma clang fp contract(off)
    const float decay = (float)0.9048374180359595;  // float32(exp(-1/10))
    const int tid = threadIdx.x;
    const int lane = tid & 63;
    const int b = blockIdx.x;
    const int pix0 = b * PIXB;

    __shared__ alignas(16) unsigned lds_hist[HIST_W];
    __shared__ unsigned lds_arr[T_TOTAL];
    __shared__ unsigned lds_tot[T_TOTAL];

    for (int i = tid; i < HIST_W; i += STHR) lds_hist[i] = 0u;
    if (tid < T_TOTAL) { lds_arr[tid] = 0u; lds_tot[tid] = 0u; }
    __syncthreads();

    {
        const int e0 = (int)seg_base[b];
        const int e1 = (int)seg_base[b + 1];
        for (int i = e0 + tid; i < e1; i += STHR) {
            unsigned lb = seg[i];
            atomicAdd(&lds_hist[lb >> 1], 1u << ((lb & 1u) << 4));
        }
    }
    __syncthreads();

    const bool has1 = tid < (NGROUP4 - STHR);
    float4 mem0 = make_float4(0.f, 0.f, 0.f, 0.f);
    float4 mem1 = make_float4(0.f, 0.f, 0.f, 0.f);
    float thr = 1.0f;

    float4 f0, f1;
    {
        uint2 w01 = *(const uint2*)&lds_hist[tid << 1];
        f0 = make_float4((float)(w01.x & 0xFFFFu), (float)(w01.x >> 16),
                         (float)(w01.y & 0xFFFFu), (float)(w01.y >> 16));
        if (has1) {
            uint2 v = *(const uint2*)&lds_hist[(tid + STHR) << 1];
            f1 = make_float4((float)(v.x & 0xFFFFu), (float)(v.x >> 16),
                             (float)(v.y & 0xFFFFu), (float)(v.y >> 16));
        } else f1 = make_float4(0.f, 0.f, 0.f, 0.f);
    }

    for (int s = 0;; ++s) {
        float* ob = out + (size_t)s * FRAME + pix0;
        int cnt = 0;

        {
            float4 m, spk;
            m.x = mem0.x + f0.x;
            m.y = mem0.y + f0.y;
            m.z = mem0.z + f0.z;
            m.w = mem0.w + f0.w;
            spk.x = (m.x >= thr) ? 1.0f : 0.0f;
            spk.y = (m.y >= thr) ? 1.0f : 0.0f;
            spk.z = (m.z >= thr) ? 1.0f : 0.0f;
            spk.w = (m.w >= thr) ? 1.0f : 0.0f;
            ((float4*)ob)[tid] = spk;
            mem0.x = m.x - spk.x * thr;
            mem0.y = m.y - spk.y * thr;
            mem0.z = m.z - spk.z * thr;
            mem0.w = m.w - spk.w * thr;
            cnt += (int)spk.x + (int)spk.y + (int)spk.z + (int)spk.w;
        }
        if (has1) {
            int g = tid + STHR;
            float4 m, spk;
            m.x = mem1.x + f1.x;
            m.y = mem1.y + f1.y;
            m.z = mem1.z + f1.z;
            m.w = mem1.w + f1.w;
            spk.x = (m.x >= thr) ? 1.0f : 0.0f;
            spk.y = (m.y >= thr) ? 1.0f : 0.0f;
            spk.z = (m.z >= thr) ? 1.0f : 0.0f;
            spk.w = (m.w >= thr) ? 1.0f : 0.0f;
            ((float4*)ob)[g] = spk;
            mem1.x = m.x - spk.x * thr;
            mem1.y = m.y - spk.y * thr;
            mem1.z = m.z - spk.z * thr;
            mem1.w = m.w - spk.w * thr;
            cnt += (int)spk.x + (int)spk.y + (int)spk.z + (int)spk.w;
        }

        if (s == T_TOTAL - 1) break;

        for (int off = 32; off > 0; off >>= 1) cnt += __shfl_down(cnt, off, 64);

        // ---- arrive phase (leader only; no polling yet) ----
        bool last = false;
        const int g1 = b >> 4;
        if (lane == 0) {
            unsigned old = __hip_atomic_fetch_add(&lds_arr[s],
                               (unsigned)cnt + (1u << 16),
                               __ATOMIC_RELAXED, __HIP_MEMORY_SCOPE_WORKGROUP);
            if ((old >> 16) == SWPB - 1) {
                last = true;
                unsigned bc = (old + (unsigned)cnt) & 0xFFFFu;
                unsigned long long a1 = __hip_atomic_fetch_add(
                    &g_n1[s][g1][0], (unsigned long long)bc + ARRIVE64,
                    __ATOMIC_RELAXED, __HIP_MEMORY_SCOPE_AGENT);
                if ((unsigned)(a1 >> 32) == 15u) {
                    unsigned c1 = (unsigned)a1 + bc;
                    const int g2 = g1 >> 4;
                    unsigned long long a2 = __hip_atomic_fetch_add(
                        &g_n2[s][g2][0], (unsigned long long)c1 + ARRIVE64,
                        __ATOMIC_RELAXED, __HIP_MEMORY_SCOPE_AGENT);
                    if ((unsigned)(a2 >> 32) == 15u) {
                        unsigned c2 = (unsigned)a2 + c1;
                        unsigned long long a3 = __hip_atomic_fetch_add(
                            &g_n3[s][0], (unsigned long long)c2 + ARRIVE64,
                            __ATOMIC_RELAXED, __HIP_MEMORY_SCOPE_AGENT);
                        if ((unsigned)(a3 >> 32) == 3u) {
                            unsigned tot = (unsigned)a3 + c2;
                            for (int g = 0; g < 64; ++g)
                                __hip_atomic_store(&g_relg[s][g][0], tot + 1u,
                                    __ATOMIC_RELAXED, __HIP_MEMORY_SCOPE_AGENT);
                        }
                    }
                }
            }
        }

        // ---- prefetch next frame + pre-decay, under the barrier shadow ----
        {
            const int sn = s + 1;
            if (sn < T_EVT) {
                uint2 w01 = *(const uint2*)&lds_hist[sn * 900 + (tid << 1)];
                f0 = make_float4((float)(w01.x & 0xFFFFu), (float)(w01.x >> 16),
                                 (float)(w01.y & 0xFFFFu), (float)(w01.y >> 16));
                if (has1) {
                    uint2 v = *(const uint2*)&lds_hist[sn * 900 + ((tid + STHR) << 1)];
                    f1 = make_float4((float)(v.x & 0xFFFFu), (float)(v.x >> 16),
                                     (float)(v.y & 0xFFFFu), (float)(v.y >> 16));
                }
            } else {
                f0 = make_float4(0.f, 0.f, 0.f, 0.f);
                f1 = make_float4(0.f, 0.f, 0.f, 0.f);
            }
            mem0.x = mem0.x * decay; mem0.y = mem0.y * decay;
            mem0.z = mem0.z * decay; mem0.w = mem0.w * decay;
            mem1.x = mem1.x * decay; mem1.y = mem1.y * decay;
            mem1.z = mem1.z * decay; mem1.w = mem1.w * decay;
        }
        __builtin_amdgcn_sched_barrier(0);   // keep prefetch before the poll

        // ---- poll phase ----
        unsigned total = 0u;
        if (lane == 0) {
            unsigned f;
            if (last) {
                do {
                    __builtin_amdgcn_s_sleep(1);
                    f = __hip_atomic_load(&g_relg[s][g1][0], __ATOMIC_RELAXED,
                                          __HIP_MEMORY_SCOPE_AGENT);
                } while (f == 0u);
                total = f - 1u;
                __hip_atomic_store(&lds_tot[s], f,
                                   __ATOMIC_RELAXED, __HIP_MEMORY_SCOPE_WORKGROUP);
            } else {
                unsigned f2;
                do {
                    __builtin_amdgcn_s_sleep(1);
                    f2 = __hip_atomic_load(&lds_tot[s], __ATOMIC_RELAXED,
                                           __HIP_MEMORY_SCOPE_WORKGROUP);
                } while (f2 == 0u);
                total = f2 - 1u;
            }
        }
        total = (unsigned)__shfl((int)total, 0, 64);
        float rate = (float)total / 1843200.0f;
        thr = thr + 0.1f * (rate - 0.1f);
        thr = fminf(fmaxf(thr, 0.1f), 10.0f);
    }
}

// ======================= old (fallback) path =======================
__global__ void scatter_kernel(const int* __restrict__ x, const int* __restrict__ y,
                               const int* __restrict__ p, const float* __restrict__ t,
                               unsigned* __restrict__ hist32, int n) {
    int i = blockIdx.x * blockDim.x + threadIdx.x;
    if (i >= n) return;
    float tmin = key2f(g_minkey);
    float tmax = key2f(g_maxkey);
    int ti = event_bin_t(t[i], tmin, tmax);
    int pix = event_pixel(x[i], y[i], p[i]);
    size_t bidx = (size_t)ti * FRAME + pix;
    atomicAdd(hist32 + (bidx >> 1), 1u << ((bidx & 1) << 4));
}

__global__ __launch_bounds__(ONTHR) void scan_old(float* __restrict__ out) {
#pragma clang fp contract(off)
    const float decay = (float)0.9048374180359595;
    const int gtid = blockIdx.x * ONTHR + threadIdx.x;
    const int lane = threadIdx.x & 63;
    const uint2 uz2 = make_uint2(0u, 0u);
    float4 mem0 = make_float4(0.f, 0.f, 0.f, 0.f);
    float4 mem1 = make_float4(0.f, 0.f, 0.f, 0.f);
    const bool has1 = (gtid + ONT) < FRAME4;
    float thr = 1.0f;
    const uint2* hist2 = (const uint2*)(out + (size_t)T_EVT * FRAME);
    __shared__ unsigned lds_arr[T_TOTAL];
    __shared__ unsigned lds_tot[T_TOTAL];
    if (threadIdx.x < T_TOTAL) { lds_arr[threadIdx.x] = 0u; lds_tot[threadIdx.x] = 0u; }
    __syncthreads();
    uint2 u0 = hist2[gtid];
    uint2 u1 = has1 ? hist2[gtid + ONT] : uz2;
    for (int s = 0; s < T_TOTAL; ++s) {
        float4* o4 = (float4*)(out + (size_t)s * FRAME);
        int cnt = 0;
        {
            float4 m, spk;
            m.x = mem0.x * decay; m.x = m.x + (float)(u0.x & 0xFFFFu);
            m.y = mem0.y * decay; m.y = m.y + (float)(u0.x >> 16);
            m.z = mem0.z * decay; m.z = m.z + (float)(u0.y & 0xFFFFu);
            m.w = mem0.w * decay; m.w = m.w + (float)(u0.y >> 16);
            spk.x = (m.x >= thr) ? 1.0f : 0.0f;
            spk.y = (m.y >= thr) ? 1.0f : 0.0f;
            spk.z = (m.z >= thr) ? 1.0f : 0.0f;
            spk.w = (m.w >= thr) ? 1.0f : 0.0f;
            o4[gtid] = spk;
            mem0.x = m.x - spk.x * thr; mem0.y = m.y - spk.y * thr;
            mem0.z = m.z - spk.z * thr; mem0.w = m.w - spk.w * thr;
            cnt += (int)spk.x + (int)spk.y + (int)spk.z + (int)spk.w;
        }
        if (has1) {
            float4 m, spk;
            m.x = mem1.x * decay; m.x = m.x + (float)(u1.x & 0xFFFFu);
            m.y = mem1.y * decay; m.y = m.y + (float)(u1.x >> 16);
            m.z = mem1.z * decay; m.z = m.z + (float)(u1.y & 0xFFFFu);
            m.w = mem1.w * decay; m.w = m.w + (float)(u1.y >> 16);
            spk.x = (m.x >= thr) ? 1.0f : 0.0f;
            spk.y = (m.y >= thr) ? 1.0f : 0.0f;
            spk.z = (m.z >= thr) ? 1.0f : 0.0f;
            spk.w = (m.w >= thr) ? 1.0f : 0.0f;
            o4[gtid + ONT] = spk;
            mem1.x = m.x - spk.x * thr; mem1.y = m.y - spk.y * thr;
            mem1.z = m.z - spk.z * thr; mem1.w = m.w - spk.w * thr;
            cnt += (int)spk.x + (int)spk.y + (int)spk.z + (int)spk.w;
        }
        if (s + 1 < T_EVT) {
            const uint2* hn = hist2 + (size_t)(s + 1) * FRAME4;
            u0 = hn[gtid];
            u1 = has1 ? hn[gtid + ONT] : uz2;
        } else { u0 = uz2; u1 = uz2; }
        if (s == T_TOTAL - 1) break;
        for (int off = 32; off > 0; off >>= 1) cnt += __shfl_down(cnt, off, 64);
        unsigned total = 0u;
        if (lane == 0) {
            unsigned old = __hip_atomic_fetch_add(&lds_arr[s],
                               (unsigned)cnt + (1u << 16),
                               __ATOMIC_RELAXED, __HIP_MEMORY_SCOPE_WORKGROUP);
            if ((old >> 16) == ONWPB - 1) {
                unsigned bc = (old + (unsigned)cnt) & 0xFFFFu;
                const int gid = blockIdx.x >> 4;
                unsigned long long gold = __hip_atomic_fetch_add(
                    &g_grp[s][gid][0], (unsigned long long)bc + ARRIVE64,
                    __ATOMIC_RELAXED, __HIP_MEMORY_SCOPE_AGENT);
                if ((unsigned)(gold >> 32) == 15u) {
                    unsigned gc = (unsigned)gold + bc;
                    unsigned long long told = __hip_atomic_fetch_add(
                        &g_top[s][0], (unsigned long long)gc + ARRIVE64,
                        __ATOMIC_RELAXED, __HIP_MEMORY_SCOPE_AGENT);
                    if ((unsigned)(told >> 32) == 15u) {
                        unsigned tot = (unsigned)told + gc;
                        __hip_atomic_store(&g_rel[s][0], tot + 1u,
                                           __ATOMIC_RELAXED, __HIP_MEMORY_SCOPE_AGENT);
                    }
                }
                unsigned f;
                do {
                    __builtin_amdgcn_s_sleep(1);
                    f = __hip_atomic_load(&g_rel[s][0], __ATOMIC_RELAXED,
                                          __HIP_MEMORY_SCOPE_AGENT);
                } while (f == 0u);
                total = f - 1u;
                __hip_atomic_store(&lds_tot[s], f,
                                   __ATOMIC_RELAXED, __HIP_MEMORY_SCOPE_WORKGROUP);
            } else {
                unsigned f;
                do {
                    __builtin_amdgcn_s_sleep(1);
                    f = __hip_atomic_load(&lds_tot[s], __ATOMIC_RELAXED,
                                          __HIP_MEMORY_SCOPE_WORKGROUP);
                } while (f == 0u);
                total = f - 1u;
            }
        }
        total = (unsigned)__shfl((int)total, 0, 64);
        float rate = (float)total / 1843200.0f;
        thr = thr + 0.1f * (rate - 0.1f);
        thr = fminf(fmaxf(thr, 0.1f), 10.0f);
    }
}

extern "C" void kernel_launch(void* const* d_in, const int* in_sizes, int n_in,
                              void* d_out, int out_size, void* d_ws, size_t ws_size,
                              hipStream_t stream) {
    const int*   x = (const int*)d_in[0];
    const int*   y = (const int*)d_in[1];
    const int*   p = (const int*)d_in[2];
    const float* t = (const float*)d_in[3];
    float* out = (float*)d_out;
    const int n = in_sizes[0];

    const int chunk = (((n + RBLK - 1) / RBLK) + 3) & ~3;
    if (d_ws != nullptr && ws_size >= WS_NEED(n) && chunk <= MAXM) {
        unsigned* mat = (unsigned*)((char*)d_ws + MAT_OFF);
        unsigned* colsum = (unsigned*)((char*)d_ws + CS_OFF);
        unsigned* seg_base = (unsigned*)((char*)d_ws + SB_OFF);
        unsigned* keys = (unsigned*)((char*)d_ws + KEY_OFF);
        unsigned short* seg = (unsigned short*)((char*)d_ws + SEG_OFF(n));

        passA_kernel<<<RBLK, RTHR, 0, stream>>>(x, y, p, t, mat, keys, n);
        offsets_kernel<<<OBLK, 1024, 0, stream>>>(mat, colsum);
        passB_kernel<<<RBLK, RTHR, 0, stream>>>(keys, t, mat, colsum, seg_base, seg, n);

        dim3 g(SBLK), b(STHR);
        void* args[] = { (void*)&out, (void*)&seg, (void*)&seg_base };
        hipLaunchCooperativeKernel((void*)scan_new, g, b, args, 0, stream);
    } else {
        init_kernel<<<64, 256, 0, stream>>>();
        unsigned* hist32 = (unsigned*)(out + (size_t)T_EVT * FRAME);
        minmax_zero_kernel<<<1024, 256, 0, stream>>>(t, n, (uint4*)hist32);
        scatter_kernel<<<(n + 255) / 256, 256, 0, stream>>>(x, y, p, t, hist32, n);
        dim3 g(ONBLK), b(ONTHR);
        void* args[] = { (void*)&out };
        hipLaunchCooperativeKernel((void*)scan_old, g, b, args, 0, stream);
    }
}

// Round 8
// 309.687 us; speedup vs baseline: 1.0033x; 1.0033x over previous
//
#include <hip/hip_runtime.h>
#include <cstddef>

#define HH 720
#define WW 1280
#define FRAME 1843200            // 2*720*1280
#define FRAME4 460800            // FRAME/4
#define T_EVT 10
#define T_TOTAL 20
#define ARRIVE64 (1ULL << 32)

// ---------- old (fallback) path config ----------
#define ONBLK 256
#define ONTHR 1024
#define ONWPB 16
#define ONT (ONBLK * ONTHR)

// ---------- new path config ----------
#define SBLK 1024                // scan blocks (4 per CU)
#define STHR 256                 // scan threads per block (4 waves)
#define SWPB 4
#define PIXB 1800                // pixels per scan block
#define NGROUP4 450              // float4 groups per block (1800/4)
#define HIST_W 9000              // LDS hist words (18000 u16)
#define RBLK 512                 // passA/passB blocks / mat rows
#define RTHR 1024
#define NBUCKET 1024
#define EPT 8                    // records/thread (8*1024=8192 >= chunk4)
#define MAXM (EPT * RTHR)
#define OBLK 16
#define OROWG 16                 // row groups (threads >> 6)
#define OROWS 32                 // rows per thread (512/16)

// ws layout (bytes), all 256-aligned
#define MAT_OFF   0u                           // u32[512*1024] = 2 MB
#define CS_OFF    (512u * 1024u * 4u)          // u32[1024] column sums
#define SB_OFF    (CS_OFF + 4096u)             // u32[1025] seg bases
#define KEY_OFF   (SB_OFF + 8192u)             // u32[n] pix keys
#define SEG_OFF(n) (KEY_OFF + 4u * (unsigned)(n))        // u16[n]
#define WS_NEED(n) ((size_t)SEG_OFF(n) + 2ull * (size_t)(n) + 256ull)

// Persistent device globals.
__device__ unsigned g_minkey;
__device__ unsigned g_maxkey;
// per-block minmax partials (plain stores; fully overwritten by passA's 512
// blocks each run, reduced by offsets block 0). Cross-kernel visibility via
// kernel boundaries only (R18 lesson).
__device__ unsigned g_part_mn[RBLK];
__device__ unsigned g_part_mx[RBLK];
// old-path tree (R8, proven)
__device__ unsigned long long g_grp[T_TOTAL][16][16];
__device__ unsigned long long g_top[T_TOTAL][16];
__device__ unsigned g_rel[T_TOTAL][32];
// scan_new tree: 1024 -> 64 -> 4 -> 1, fan-out to 64 group-release words
__device__ unsigned long long g_n1[T_TOTAL][64][16];
__device__ unsigned long long g_n2[T_TOTAL][4][16];
__device__ unsigned long long g_n3[T_TOTAL][16];
__device__ unsigned g_relg[T_TOTAL][64][32];   // [s][group][0]: total+1

__device__ __forceinline__ unsigned f2key(float f) {
    unsigned b = __float_as_uint(f);
    return b ^ ((unsigned)(((int)b) >> 31) | 0x80000000u);
}
__device__ __forceinline__ float key2f(unsigned k) {
    unsigned b = (k & 0x80000000u) ? (k ^ 0x80000000u) : ~k;
    return __uint_as_float(b);
}

// Exact reference bin: ((t-tmin)/(tmax-tmin))*(10-1e-6), trunc, clip.
__device__ __forceinline__ int event_bin_t(float tv, float tmin, float tmax) {
#pragma clang fp contract(off)
    float tn;
    if (tmax > tmin) tn = (tv - tmin) / (tmax - tmin) * (float)(10.0 - 1e-6);
    else tn = 0.0f;
    int ti = (int)tn;
    return ti < 0 ? 0 : (ti > T_EVT - 1 ? T_EVT - 1 : ti);
}
__device__ __forceinline__ int event_pixel(int xi, int yi, int ci) {
    xi = xi < 0 ? 0 : (xi > WW - 1 ? WW - 1 : xi);
    yi = yi < 0 ? 0 : (yi > HH - 1 ? HH - 1 : yi);
    return ci * (HH * WW) + yi * WW + xi;
}

// init_kernel: FALLBACK PATH ONLY.
__global__ void init_kernel() {
    const int gtid = blockIdx.x * blockDim.x + threadIdx.x;
    const int gs = gridDim.x * blockDim.x;
    if (gtid == 0) { g_minkey = 0xFFFFFFFFu; g_maxkey = 0u; }
    unsigned long long* a = &g_grp[0][0][0];
    for (int i = gtid; i < T_TOTAL * 16 * 16; i += gs) a[i] = 0ull;
    unsigned long long* b = &g_top[0][0];
    for (int i = gtid; i < T_TOTAL * 16; i += gs) b[i] = 0ull;
    unsigned* c = &g_rel[0][0];
    for (int i = gtid; i < T_TOTAL * 32; i += gs) c[i] = 0u;
}

// ======================= shared: t min/max (fallback path) ==============
__device__ __forceinline__ void minmax_body(const float* __restrict__ t, int n,
                                            int gtid, int gstride) {
    unsigned mn = 0xFFFFFFFFu, mx = 0u;
    const int n4 = n >> 2;
    const float4* t4 = (const float4*)t;
    for (int i = gtid; i < n4; i += gstride) {
        float4 tv = t4[i];
        unsigned k0 = f2key(tv.x), k1 = f2key(tv.y);
        unsigned k2 = f2key(tv.z), k3 = f2key(tv.w);
        unsigned a = k0 < k1 ? k0 : k1, b = k2 < k3 ? k2 : k3;
        unsigned c = a < b ? a : b;
        mn = mn < c ? mn : c;
        a = k0 > k1 ? k0 : k1; b = k2 > k3 ? k2 : k3;
        c = a > b ? a : b;
        mx = mx > c ? mx : c;
    }
    for (int i = (n4 << 2) + gtid; i < n; i += gstride) {
        unsigned k = f2key(t[i]);
        mn = mn < k ? mn : k;
        mx = mx > k ? mx : k;
    }
    for (int off = 32; off > 0; off >>= 1) {
        unsigned omn = (unsigned)__shfl_down((int)mn, off, 64);
        unsigned omx = (unsigned)__shfl_down((int)mx, off, 64);
        mn = mn < omn ? mn : omn;
        mx = mx > omx ? mx : omx;
    }
    __shared__ unsigned smn[16], smx[16];
    int lane = threadIdx.x & 63, wv = threadIdx.x >> 6;
    if (lane == 0) { smn[wv] = mn; smx[wv] = mx; }
    __syncthreads();
    if (threadIdx.x == 0) {
        int nw = blockDim.x >> 6;
        for (int i = 1; i < nw; ++i) {
            mn = mn < smn[i] ? mn : smn[i];
            mx = mx > smx[i] ? mx : smx[i];
        }
        atomicMin(&g_minkey, mn);
        atomicMax(&g_maxkey, mx);
    }
}

__global__ void minmax_zero_kernel(const float* __restrict__ t, int n,
                                   uint4* __restrict__ hist16v) {
    const int gtid = blockIdx.x * blockDim.x + threadIdx.x;
    const int gstride = gridDim.x * blockDim.x;
    const uint4 z = make_uint4(0u, 0u, 0u, 0u);
    const int nz = T_EVT * FRAME / 8;
    for (int i = gtid; i < nz; i += gstride) hist16v[i] = z;
    minmax_body(t, n, gtid, gstride);
}

// ======================= new path: counting sort =======================
// passA (R19, proven): 4-wide vectorized event loop; chunk multiple of 4.
__global__ __launch_bounds__(RTHR) void passA_kernel(
        const int* __restrict__ x, const int* __restrict__ y,
        const int* __restrict__ p, const float* __restrict__ t,
        unsigned* __restrict__ mat, unsigned* __restrict__ keys, int n) {
    __shared__ unsigned cnt[NBUCKET];
    const int gtid = blockIdx.x * blockDim.x + threadIdx.x;
    const int gs = gridDim.x * blockDim.x;
    {   // zero scan_new's sync tree (kernel boundary = visibility for scan)
        unsigned long long* z1 = &g_n1[0][0][0];
        for (int i = gtid; i < T_TOTAL * 64 * 16; i += gs) z1[i] = 0ull;
        unsigned long long* z2 = &g_n2[0][0][0];
        for (int i = gtid; i < T_TOTAL * 4 * 16; i += gs) z2[i] = 0ull;
        unsigned long long* z3 = &g_n3[0][0];
        for (int i = gtid; i < T_TOTAL * 16; i += gs) z3[i] = 0ull;
        unsigned* z4 = &g_relg[0][0][0];
        for (int i = gtid; i < T_TOTAL * 64 * 32; i += gs) z4[i] = 0u;
    }
    for (int i = threadIdx.x; i < NBUCKET; i += blockDim.x) cnt[i] = 0u;
    __syncthreads();
    const int chunk = (((n + RBLK - 1) / RBLK) + 3) & ~3;   // mult of 4
    const int s0 = blockIdx.x * chunk;
    const int s1 = min(n, s0 + chunk);
    unsigned mn = 0xFFFFFFFFu, mx = 0u;
    for (int base = s0 + (threadIdx.x << 2); base < s1; base += (RTHR << 2)) {
        if (base + 4 <= s1) {
            int4 xv = *(const int4*)(x + base);
            int4 yv = *(const int4*)(y + base);
            int4 pv = *(const int4*)(p + base);
            float4 tv = *(const float4*)(t + base);
            int p0 = event_pixel(xv.x, yv.x, pv.x);
            int p1 = event_pixel(xv.y, yv.y, pv.y);
            int p2 = event_pixel(xv.z, yv.z, pv.z);
            int p3 = event_pixel(xv.w, yv.w, pv.w);
            *(int4*)(keys + base) = make_int4(p0, p1, p2, p3);
            atomicAdd(&cnt[p0 / PIXB], 1u);
            atomicAdd(&cnt[p1 / PIXB], 1u);
            atomicAdd(&cnt[p2 / PIXB], 1u);
            atomicAdd(&cnt[p3 / PIXB], 1u);
            unsigned k0 = f2key(tv.x), k1 = f2key(tv.y);
            unsigned k2 = f2key(tv.z), k3 = f2key(tv.w);
            unsigned a = k0 < k1 ? k0 : k1, b = k2 < k3 ? k2 : k3;
            unsigned c = a < b ? a : b;
            mn = mn < c ? mn : c;
            a = k0 > k1 ? k0 : k1; b = k2 > k3 ? k2 : k3;
            c = a > b ? a : b;
            mx = mx > c ? mx : c;
        } else {
            for (int e = 0; e < 4; ++e) {
                int i = base + e;
                if (i < s1) {
                    int pix = event_pixel(x[i], y[i], p[i]);
                    keys[i] = (unsigned)pix;
                    atomicAdd(&cnt[pix / PIXB], 1u);
                    unsigned k = f2key(t[i]);
                    mn = mn < k ? mn : k;
                    mx = mx > k ? mx : k;
                }
            }
        }
    }
    // block minmax reduce -> per-block partial (plain store)
    for (int off = 32; off > 0; off >>= 1) {
        unsigned omn = (unsigned)__shfl_down((int)mn, off, 64);
        unsigned omx = (unsigned)__shfl_down((int)mx, off, 64);
        mn = mn < omn ? mn : omn;
        mx = mx > omx ? mx : omx;
    }
    __shared__ unsigned smn[RTHR / 64], smx[RTHR / 64];
    const int lane = threadIdx.x & 63, wv = threadIdx.x >> 6;
    if (lane == 0) { smn[wv] = mn; smx[wv] = mx; }
    __syncthreads();
    if (threadIdx.x == 0) {
#pragma unroll
        for (int i = 1; i < RTHR / 64; ++i) {
            mn = mn < smn[i] ? mn : smn[i];
            mx = mx > smx[i] ? mx : smx[i];
        }
        g_part_mn[blockIdx.x] = mn;
        g_part_mx[blockIdx.x] = mx;
    }
    for (int i = threadIdx.x; i < NBUCKET; i += blockDim.x)
        mat[blockIdx.x * NBUCKET + i] = cnt[i];
}

// offsets v2 (R17, proven): 16 blocks x 1024 thr; block owns 64 CONSECUTIVE
// bucket columns; coalesced two-pass column scan. Block 0 also reduces the
// 512 minmax partials -> g_minkey/g_maxkey.
__global__ __launch_bounds__(1024) void offsets_kernel(
        unsigned* __restrict__ mat, unsigned* __restrict__ colsum) {
    const int t = threadIdx.x;
    const int c = t & 63;            // column within block's group
    const int rg = t >> 6;           // row group 0..15
    const int j = blockIdx.x * 64 + c;
    __shared__ unsigned part[OROWG][64];
    unsigned sum = 0u;
    for (int k = 0; k < OROWS; ++k)
        sum += mat[(rg * OROWS + k) * NBUCKET + j];
    part[rg][c] = sum;
    __syncthreads();
    if (rg == 0) {                   // thread c: serial scan of 16 partials
        unsigned run = 0u;
#pragma unroll
        for (int g = 0; g < OROWG; ++g) {
            unsigned v = part[g][c];
            part[g][c] = run;
            run += v;
        }
        colsum[j] = run;             // inclusive total of column j
    }
    __syncthreads();
    unsigned running = part[rg][c];
    for (int k = 0; k < OROWS; ++k) {
        const int idx = (rg * OROWS + k) * NBUCKET + j;
        unsigned v = mat[idx];
        mat[idx] = running;          // exclusive prefix within column
        running += v;
    }

    if (blockIdx.x == 0) {           // minmax partial reduce (512 partials)
        const int lane = t & 63, wv = t >> 6;
        unsigned mn = 0xFFFFFFFFu, mx = 0u;
        if (t < RBLK) { mn = g_part_mn[t]; mx = g_part_mx[t]; }
        for (int off = 32; off > 0; off >>= 1) {
            unsigned omn = (unsigned)__shfl_down((int)mn, off, 64);
            unsigned omx = (unsigned)__shfl_down((int)mx, off, 64);
            mn = mn < omn ? mn : omn;
            mx = mx > omx ? mx : omx;
        }
        __shared__ unsigned smn2[16], smx2[16];
        if (lane == 0) { smn2[wv] = mn; smx2[wv] = mx; }
        __syncthreads();
        if (t == 0) {
#pragma unroll
            for (int k = 1; k < 16; ++k) {
                mn = mn < smn2[k] ? mn : smn2[k];
                mx = mx > smx2[k] ? mx : smx2[k];
            }
            g_minkey = mn;
            g_maxkey = mx;
        }
    }
}

// passB (R20): local bucket counts DERIVED from mat instead of re-counted
// with LDS atomics. After offsets_kernel, mat[r][j] is the exclusive column
// prefix, so block bid's own count of bucket j is mat[bid+1][j]-mat[bid][j]
// (last row: colsum[j]-mat[511][j]) -- numerically identical to local
// counting, so all offsets/ranks/seg are unchanged. Removes 8 random-bucket
// LDS atomicAdds per thread (half the kernel's LDS-atomic traffic) plus two
// __syncthreads rounds; phase 1 is now atomic-free.
__global__ __launch_bounds__(RTHR) void passB_kernel(
        const unsigned* __restrict__ keys, const float* __restrict__ t,
        const unsigned* __restrict__ mat, const unsigned* __restrict__ colsum,
        unsigned* __restrict__ seg_base_out,
        unsigned short* __restrict__ seg, int n) {
    __shared__ unsigned base[NBUCKET];   // global run start -> gdst
    __shared__ unsigned lrun[NBUCKET];   // rank counter (seeded w/ excl scan)
    __shared__ unsigned wt2[RTHR / 64];
    __shared__ unsigned wt3[RTHR / 64];
    __shared__ unsigned short sorted[MAXM];  // 16 KB
    __shared__ unsigned short sbkt[MAXM];    // 16 KB
    const int j = threadIdx.x;           // RTHR == NBUCKET
    const int lane = j & 63, wv = j >> 6;
    {   // prologue: colsum excl-scan -> ex (global col base); mat-derived
        // local count cntv; local excl-scan of cntv -> ex2; set base & lrun.
        unsigned v = colsum[j];
        unsigned gbase = mat[blockIdx.x * NBUCKET + j];
        unsigned cntv = ((blockIdx.x < RBLK - 1)
                             ? mat[(blockIdx.x + 1) * NBUCKET + j]
                             : v) - gbase;     // bid=511: colsum - mat[511]
        unsigned incl = v;
        unsigned incl2 = cntv;
        for (int off = 1; off < 64; off <<= 1) {
            unsigned o = (unsigned)__shfl_up((int)incl, off, 64);
            unsigned o2 = (unsigned)__shfl_up((int)incl2, off, 64);
            if (lane >= off) { incl += o; incl2 += o2; }
        }
        if (lane == 63) { wt2[wv] = incl; wt3[wv] = incl2; }
        __syncthreads();
        if (j == 0) {
            unsigned run = 0, run2 = 0;
#pragma unroll
            for (int k = 0; k < RTHR / 64; ++k) {
                unsigned tmp = wt2[k]; wt2[k] = run; run += tmp;
                unsigned tmp2 = wt3[k]; wt3[k] = run2; run2 += tmp2;
            }
        }
        __syncthreads();
        unsigned ex = incl - v + wt2[wv];        // global col excl prefix
        unsigned ex2 = incl2 - cntv + wt3[wv];   // local bucket excl prefix
        base[j] = gbase + ex - ex2;  // gdst: global dst = base + sorted idx
        lrun[j] = ex2;               // rank counter seed
        if (blockIdx.x == 0) {
            seg_base_out[j] = ex;
            if (j == NBUCKET - 1) seg_base_out[NBUCKET] = ex + v;
        }
    }
    __syncthreads();
    const float tmin = key2f(g_minkey);
    const float tmax = key2f(g_maxkey);
    const int chunk = (((n + RBLK - 1) / RBLK) + 3) & ~3;   // mult of 4
    const int s0 = blockIdx.x * chunk;
    const int s1 = min(n, s0 + chunk);
    const int m = s1 - s0;               // <= MAXM (launcher-guarded)

    // phase 1: vectorized read, records in registers -- NO atomics now.
    unsigned rec[EPT];
#pragma unroll
    for (int k = 0; k < EPT / 4; ++k) {
        const int ibase = s0 + ((k * RTHR + j) << 2);
#pragma unroll
        for (int e = 0; e < 4; ++e) rec[k * 4 + e] = 0xFFFFFFFFu;
        if (ibase + 4 <= s1) {
            uint4 kv = *(const uint4*)(keys + ibase);
            float4 tv = *(const float4*)(t + ibase);
            unsigned pxs[4] = { kv.x, kv.y, kv.z, kv.w };
            float ts[4] = { tv.x, tv.y, tv.z, tv.w };
#pragma unroll
            for (int e = 0; e < 4; ++e) {
                int pix = (int)pxs[e];
                int ti = event_bin_t(ts[e], tmin, tmax);
                int bkt = pix / PIXB;
                int lb = ti * PIXB + (pix - bkt * PIXB);   // < 18000
                rec[k * 4 + e] = ((unsigned)bkt << 16) | (unsigned)lb;
            }
        } else if (ibase < s1) {
            for (int e = 0; e < 4; ++e) {
                int i = ibase + e;
                if (i < s1) {
                    int pix = (int)keys[i];
                    int ti = event_bin_t(t[i], tmin, tmax);
                    int bkt = pix / PIXB;
                    int lb = ti * PIXB + (pix - bkt * PIXB);
                    rec[k * 4 + e] = ((unsigned)bkt << 16) | (unsigned)lb;
                }
            }
        }
    }
    // phase 3: rank from registers -> LDS sorted array (lrun seeded above)
#pragma unroll
    for (int k = 0; k < EPT; ++k) {
        unsigned r0 = rec[k];
        if (r0 != 0xFFFFFFFFu) {
            unsigned bkt = r0 >> 16;
            unsigned r = atomicAdd(&lrun[bkt], 1u);
            sorted[r] = (unsigned short)(r0 & 0xFFFFu);
            sbkt[r] = (unsigned short)bkt;
        }
    }
    __syncthreads();
    // phase 4: coalesced flush (consecutive i in a bucket -> consec dst)
    for (int i = j; i < m; i += RTHR) {
        unsigned bk = sbkt[i];
        seg[base[bk] + (unsigned)i] = sorted[i];
    }
}

// Cooperative scan, 1024 blocks x 256 thr, 36 KB LDS hist (R9-R17, proven,
// byte-identical to the 309/310 us versions).
__global__ __launch_bounds__(STHR, 4) void scan_new(float* __restrict__ out,
                                                    const unsigned short* __restrict__ seg,
                                                    const unsigned* __restrict__ seg_base) {
#pragma clang fp contract(off)
    const float decay = (float)0.9048374180359595;  // float32(exp(-1/10))
    const int tid = threadIdx.x;
    const int lane = tid & 63;
    const int b = blockIdx.x;
    const int pix0 = b * PIXB;

    __shared__ alignas(16) unsigned lds_hist[HIST_W];
    __shared__ unsigned lds_arr[T_TOTAL];
    __shared__ unsigned lds_tot[T_TOTAL];

    for (int i = tid; i < HIST_W; i += STHR) lds_hist[i] = 0u;
    if (tid < T_TOTAL) { lds_arr[tid] = 0u; lds_tot[tid] = 0u; }
    __syncthreads();

    {
        const int e0 = (int)seg_base[b];
        const int e1 = (int)seg_base[b + 1];
        for (int i = e0 + tid; i < e1; i += STHR) {
            unsigned lb = seg[i];
            atomicAdd(&lds_hist[lb >> 1], 1u << ((lb & 1u) << 4));
        }
    }
    __syncthreads();

    const bool has1 = tid < (NGROUP4 - STHR);
    float4 mem0 = make_float4(0.f, 0.f, 0.f, 0.f);
    float4 mem1 = make_float4(0.f, 0.f, 0.f, 0.f);
    float thr = 1.0f;

    float4 f0, f1;
    {
        uint2 w01 = *(const uint2*)&lds_hist[tid << 1];
        f0 = make_float4((float)(w01.x & 0xFFFFu), (float)(w01.x >> 16),
                         (float)(w01.y & 0xFFFFu), (float)(w01.y >> 16));
        if (has1) {
            uint2 v = *(const uint2*)&lds_hist[(tid + STHR) << 1];
            f1 = make_float4((float)(v.x & 0xFFFFu), (float)(v.x >> 16),
                             (float)(v.y & 0xFFFFu), (float)(v.y >> 16));
        } else f1 = make_float4(0.f, 0.f, 0.f, 0.f);
    }

    for (int s = 0;; ++s) {
        float* ob = out + (size_t)s * FRAME + pix0;
        int cnt = 0;

        {
            float4 m, spk;
            m.x = mem0.x + f0.x;
            m.y = mem0.y + f0.y;
            m.z = mem0.z + f0.z;
            m.w = mem0.w + f0.w;
            spk.x = (m.x >= thr) ? 1.0f : 0.0f;
            spk.y = (m.y >= thr) ? 1.0f : 0.0f;
            spk.z = (m.z >= thr) ? 1.0f : 0.0f;
            spk.w = (m.w >= thr) ? 1.0f : 0.0f;
            ((float4*)ob)[tid] = spk;
            mem0.x = m.x - spk.x * thr;
            mem0.y = m.y - spk.y * thr;
            mem0.z = m.z - spk.z * thr;
            mem0.w = m.w - spk.w * thr;
            cnt += (int)spk.x + (int)spk.y + (int)spk.z + (int)spk.w;
        }
        if (has1) {
            int g = tid + STHR;
            float4 m, spk;
            m.x = mem1.x + f1.x;
            m.y = mem1.y + f1.y;
            m.z = mem1.z + f1.z;
            m.w = mem1.w + f1.w;
            spk.x = (m.x >= thr) ? 1.0f : 0.0f;
            spk.y = (m.y >= thr) ? 1.0f : 0.0f;
            spk.z = (m.z >= thr) ? 1.0f : 0.0f;
            spk.w = (m.w >= thr) ? 1.0f : 0.0f;
            ((float4*)ob)[g] = spk;
            mem1.x = m.x - spk.x * thr;
            mem1.y = m.y - spk.y * thr;
            mem1.z = m.z - spk.z * thr;
            mem1.w = m.w - spk.w * thr;
            cnt += (int)spk.x + (int)spk.y + (int)spk.z + (int)spk.w;
        }

        if (s == T_TOTAL - 1) break;

        for (int off = 32; off > 0; off >>= 1) cnt += __shfl_down(cnt, off, 64);

        // ---- arrive phase (leader only; no polling yet) ----
        bool last = false;
        const int g1 = b >> 4;
        if (lane == 0) {
            unsigned old = __hip_atomic_fetch_add(&lds_arr[s],
                               (unsigned)cnt + (1u << 16),
                               __ATOMIC_RELAXED, __HIP_MEMORY_SCOPE_WORKGROUP);
            if ((old >> 16) == SWPB - 1) {
                last = true;
                unsigned bc = (old + (unsigned)cnt) & 0xFFFFu;
                unsigned long long a1 = __hip_atomic_fetch_add(
                    &g_n1[s][g1][0], (unsigned long long)bc + ARRIVE64,
                    __ATOMIC_RELAXED, __HIP_MEMORY_SCOPE_AGENT);
                if ((unsigned)(a1 >> 32) == 15u) {
                    unsigned c1 = (unsigned)a1 + bc;
                    const int g2 = g1 >> 4;
                    unsigned long long a2 = __hip_atomic_fetch_add(
                        &g_n2[s][g2][0], (unsigned long long)c1 + ARRIVE64,
                        __ATOMIC_RELAXED, __HIP_MEMORY_SCOPE_AGENT);
                    if ((unsigned)(a2 >> 32) == 15u) {
                        unsigned c2 = (unsigned)a2 + c1;
                        unsigned long long a3 = __hip_atomic_fetch_add(
                            &g_n3[s][0], (unsigned long long)c2 + ARRIVE64,
                            __ATOMIC_RELAXED, __HIP_MEMORY_SCOPE_AGENT);
                        if ((unsigned)(a3 >> 32) == 3u) {
                            unsigned tot = (unsigned)a3 + c2;
                            for (int g = 0; g < 64; ++g)
                                __hip_atomic_store(&g_relg[s][g][0], tot + 1u,
                                    __ATOMIC_RELAXED, __HIP_MEMORY_SCOPE_AGENT);
                        }
                    }
                }
            }
        }

        // ---- prefetch next frame + pre-decay, under the barrier shadow ----
        {
            const int sn = s + 1;
            if (sn < T_EVT) {
                uint2 w01 = *(const uint2*)&lds_hist[sn * 900 + (tid << 1)];
                f0 = make_float4((float)(w01.x & 0xFFFFu), (float)(w01.x >> 16),
                                 (float)(w01.y & 0xFFFFu), (float)(w01.y >> 16));
                if (has1) {
                    uint2 v = *(const uint2*)&lds_hist[sn * 900 + ((tid + STHR) << 1)];
                    f1 = make_float4((float)(v.x & 0xFFFFu), (float)(v.x >> 16),
                                     (float)(v.y & 0xFFFFu), (float)(v.y >> 16));
                }
            } else {
                f0 = make_float4(0.f, 0.f, 0.f, 0.f);
                f1 = make_float4(0.f, 0.f, 0.f, 0.f);
            }
            mem0.x = mem0.x * decay; mem0.y = mem0.y * decay;
            mem0.z = mem0.z * decay; mem0.w = mem0.w * decay;
            mem1.x = mem1.x * decay; mem1.y = mem1.y * decay;
            mem1.z = mem1.z * decay; mem1.w = mem1.w * decay;
        }
        __builtin_amdgcn_sched_barrier(0);   // keep prefetch before the poll

        // ---- poll phase ----
        unsigned total = 0u;
        if (lane == 0) {
            unsigned f;
            if (last) {
                do {
                    __builtin_amdgcn_s_sleep(1);
                    f = __hip_atomic_load(&g_relg[s][g1][0], __ATOMIC_RELAXED,
                                          __HIP_MEMORY_SCOPE_AGENT);
                } while (f == 0u);
                total = f - 1u;
                __hip_atomic_store(&lds_tot[s], f,
                                   __ATOMIC_RELAXED, __HIP_MEMORY_SCOPE_WORKGROUP);
            } else {
                unsigned f2;
                do {
                    __builtin_amdgcn_s_sleep(1);
                    f2 = __hip_atomic_load(&lds_tot[s], __ATOMIC_RELAXED,
                                           __HIP_MEMORY_SCOPE_WORKGROUP);
                } while (f2 == 0u);
                total = f2 - 1u;
            }
        }
        total = (unsigned)__shfl((int)total, 0, 64);
        float rate = (float)total / 1843200.0f;
        thr = thr + 0.1f * (rate - 0.1f);
        thr = fminf(fmaxf(thr, 0.1f), 10.0f);
    }
}

// ======================= old (fallback) path =======================
__global__ void scatter_kernel(const int* __restrict__ x, const int* __restrict__ y,
                               const int* __restrict__ p, const float* __restrict__ t,
                               unsigned* __restrict__ hist32, int n) {
    int i = blockIdx.x * blockDim.x + threadIdx.x;
    if (i >= n) return;
    float tmin = key2f(g_minkey);
    float tmax = key2f(g_maxkey);
    int ti = event_bin_t(t[i], tmin, tmax);
    int pix = event_pixel(x[i], y[i], p[i]);
    size_t bidx = (size_t)ti * FRAME + pix;
    atomicAdd(hist32 + (bidx >> 1), 1u << ((bidx & 1) << 4));
}

__global__ __launch_bounds__(ONTHR) void scan_old(float* __restrict__ out) {
#pragma clang fp contract(off)
    const float decay = (float)0.9048374180359595;
    const int gtid = blockIdx.x * ONTHR + threadIdx.x;
    const int lane = threadIdx.x & 63;
    const uint2 uz2 = make_uint2(0u, 0u);
    float4 mem0 = make_float4(0.f, 0.f, 0.f, 0.f);
    float4 mem1 = make_float4(0.f, 0.f, 0.f, 0.f);
    const bool has1 = (gtid + ONT) < FRAME4;
    float thr = 1.0f;
    const uint2* hist2 = (const uint2*)(out + (size_t)T_EVT * FRAME);
    __shared__ unsigned lds_arr[T_TOTAL];
    __shared__ unsigned lds_tot[T_TOTAL];
    if (threadIdx.x < T_TOTAL) { lds_arr[threadIdx.x] = 0u; lds_tot[threadIdx.x] = 0u; }
    __syncthreads();
    uint2 u0 = hist2[gtid];
    uint2 u1 = has1 ? hist2[gtid + ONT] : uz2;
    for (int s = 0; s < T_TOTAL; ++s) {
        float4* o4 = (float4*)(out + (size_t)s * FRAME);
        int cnt = 0;
        {
            float4 m, spk;
            m.x = mem0.x * decay; m.x = m.x + (float)(u0.x & 0xFFFFu);
            m.y = mem0.y * decay; m.y = m.y + (float)(u0.x >> 16);
            m.z = mem0.z * decay; m.z = m.z + (float)(u0.y & 0xFFFFu);
            m.w = mem0.w * decay; m.w = m.w + (float)(u0.y >> 16);
            spk.x = (m.x >= thr) ? 1.0f : 0.0f;
            spk.y = (m.y >= thr) ? 1.0f : 0.0f;
            spk.z = (m.z >= thr) ? 1.0f : 0.0f;
            spk.w = (m.w >= thr) ? 1.0f : 0.0f;
            o4[gtid] = spk;
            mem0.x = m.x - spk.x * thr; mem0.y = m.y - spk.y * thr;
            mem0.z = m.z - spk.z * thr; mem0.w = m.w - spk.w * thr;
            cnt += (int)spk.x + (int)spk.y + (int)spk.z + (int)spk.w;
        }
        if (has1) {
            float4 m, spk;
            m.x = mem1.x * decay; m.x = m.x + (float)(u1.x & 0xFFFFu);
            m.y = mem1.y * decay; m.y = m.y + (float)(u1.x >> 16);
            m.z = mem1.z * decay; m.z = m.z + (float)(u1.y & 0xFFFFu);
            m.w = mem1.w * decay; m.w = m.w + (float)(u1.y >> 16);
            spk.x = (m.x >= thr) ? 1.0f : 0.0f;
            spk.y = (m.y >= thr) ? 1.0f : 0.0f;
            spk.z = (m.z >= thr) ? 1.0f : 0.0f;
            spk.w = (m.w >= thr) ? 1.0f : 0.0f;
            o4[gtid + ONT] = spk;
            mem1.x = m.x - spk.x * thr; mem1.y = m.y - spk.y * thr;
            mem1.z = m.z - spk.z * thr; mem1.w = m.w - spk.w * thr;
            cnt += (int)spk.x + (int)spk.y + (int)spk.z + (int)spk.w;
        }
        if (s + 1 < T_EVT) {
            const uint2* hn = hist2 + (size_t)(s + 1) * FRAME4;
            u0 = hn[gtid];
            u1 = has1 ? hn[gtid + ONT] : uz2;
        } else { u0 = uz2; u1 = uz2; }
        if (s == T_TOTAL - 1) break;
        for (int off = 32; off > 0; off >>= 1) cnt += __shfl_down(cnt, off, 64);
        unsigned total = 0u;
        if (lane == 0) {
            unsigned old = __hip_atomic_fetch_add(&lds_arr[s],
                               (unsigned)cnt + (1u << 16),
                               __ATOMIC_RELAXED, __HIP_MEMORY_SCOPE_WORKGROUP);
            if ((old >> 16) == ONWPB - 1) {
                unsigned bc = (old + (unsigned)cnt) & 0xFFFFu;
                const int gid = blockIdx.x >> 4;
                unsigned long long gold = __hip_atomic_fetch_add(
                    &g_grp[s][gid][0], (unsigned long long)bc + ARRIVE64,
                    __ATOMIC_RELAXED, __HIP_MEMORY_SCOPE_AGENT);
                if ((unsigned)(gold >> 32) == 15u) {
                    unsigned gc = (unsigned)gold + bc;
                    unsigned long long told = __hip_atomic_fetch_add(
                        &g_top[s][0], (unsigned long long)gc + ARRIVE64,
                        __ATOMIC_RELAXED, __HIP_MEMORY_SCOPE_AGENT);
                    if ((unsigned)(told >> 32) == 15u) {
                        unsigned tot = (unsigned)told + gc;
                        __hip_atomic_store(&g_rel[s][0], tot + 1u,
                                           __ATOMIC_RELAXED, __HIP_MEMORY_SCOPE_AGENT);
                    }
                }
                unsigned f;
                do {
                    __builtin_amdgcn_s_sleep(1);
                    f = __hip_atomic_load(&g_rel[s][0], __ATOMIC_RELAXED,
                                          __HIP_MEMORY_SCOPE_AGENT);
                } while (f == 0u);
                total = f - 1u;
                __hip_atomic_store(&lds_tot[s], f,
                                   __ATOMIC_RELAXED, __HIP_MEMORY_SCOPE_WORKGROUP);
            } else {
                unsigned f;
                do {
                    __builtin_amdgcn_s_sleep(1);
                    f = __hip_atomic_load(&lds_tot[s], __ATOMIC_RELAXED,
                                          __HIP_MEMORY_SCOPE_WORKGROUP);
                } while (f == 0u);
                total = f - 1u;
            }
        }
        total = (unsigned)__shfl((int)total, 0, 64);
        float rate = (float)total / 1843200.0f;
        thr = thr + 0.1f * (rate - 0.1f);
        thr = fminf(fmaxf(thr, 0.1f), 10.0f);
    }
}

extern "C" void kernel_launch(void* const* d_in, const int* in_sizes, int n_in,
                              void* d_out, int out_size, void* d_ws, size_t ws_size,
                              hipStream_t stream) {
    const int*   x = (const int*)d_in[0];
    const int*   y = (const int*)d_in[1];
    const int*   p = (const int*)d_in[2];
    const float* t = (const float*)d_in[3];
    float* out = (float*)d_out;
    const int n = in_sizes[0];

    const int chunk = (((n + RBLK - 1) / RBLK) + 3) & ~3;
    if (d_ws != nullptr && ws_size >= WS_NEED(n) && chunk <= MAXM) {
        unsigned* mat = (unsigned*)((char*)d_ws + MAT_OFF);
        unsigned* colsum = (unsigned*)((char*)d_ws + CS_OFF);
        unsigned* seg_base = (unsigned*)((char*)d_ws + SB_OFF);
        unsigned* keys = (unsigned*)((char*)d_ws + KEY_OFF);
        unsigned short* seg = (unsigned short*)((char*)d_ws + SEG_OFF(n));

        passA_kernel<<<RBLK, RTHR, 0, stream>>>(x, y, p, t, mat, keys, n);
        offsets_kernel<<<OBLK, 1024, 0, stream>>>(mat, colsum);
        passB_kernel<<<RBLK, RTHR, 0, stream>>>(keys, t, mat, colsum, seg_base, seg, n);

        dim3 g(SBLK), b(STHR);
        void* args[] = { (void*)&out, (void*)&seg, (void*)&seg_base };
        hipLaunchCooperativeKernel((void*)scan_new, g, b, args, 0, stream);
    } else {
        init_kernel<<<64, 256, 0, stream>>>();
        unsigned* hist32 = (unsigned*)(out + (size_t)T_EVT * FRAME);
        minmax_zero_kernel<<<1024, 256, 0, stream>>>(t, n, (uint4*)hist32);
        scatter_kernel<<<(n + 255) / 256, 256, 0, stream>>>(x, y, p, t, hist32, n);
        dim3 g(ONBLK), b(ONTHR);
        void* args[] = { (void*)&out };
        hipLaunchCooperativeKernel((void*)scan_old, g, b, args, 0, stream);
    }
}

// Round 9
// 307.699 us; speedup vs baseline: 1.0098x; 1.0065x over previous
//
#include <hip/hip_runtime.h>
#include <cstddef>

#define HH 720
#define WW 1280
#define FRAME 1843200            // 2*720*1280
#define FRAME4 460800            // FRAME/4
#define T_EVT 10
#define T_TOTAL 20
#define ARRIVE64 (1ULL << 32)

// ---------- old (fallback) path config ----------
#define ONBLK 256
#define ONTHR 1024
#define ONWPB 16
#define ONT (ONBLK * ONTHR)

// ---------- new path config ----------
#define SBLK 1024                // scan blocks (4 per CU)
#define STHR 256                 // scan threads per block (4 waves)
#define SWPB 4
#define PIXB 1800                // pixels per scan block
#define NGROUP4 450              // float4 groups per block (1800/4)
#define HIST_W 9000              // LDS hist words (18000 u16)
#define RBLK 512                 // passAB blocks / mat rows
#define RTHR 1024
#define NBUCKET 1024
#define EPT 8                    // records/thread (8*1024=8192 >= chunk4)
#define MAXM (EPT * RTHR)
#define MMBLK 128                // minmax kernel blocks
#define MMTHR 1024

// ws layout (bytes), all 256-aligned.
// R21: keys/colsum/seg_base dropped. seg is [chunk][bucket]-local, padded to
// RBLK*chunk4 entries (chunk4 <= 8192), placed at KEY_OFF (old keys slot).
#define MAT_OFF   0u                           // u32[512*1024] = 2 MB
#define MMX_OFF   (512u * 1024u * 4u)          // u32 minmax accum (256 B)
#define KEY_OFF   (MMX_OFF + 4096u)
#define WS_NEED(chunk) ((size_t)KEY_OFF + 2ull * RBLK * (size_t)(chunk) + 256ull)

// Persistent device globals.
__device__ unsigned g_minkey;
__device__ unsigned g_maxkey;
// old-path tree (R8, proven)
__device__ unsigned long long g_grp[T_TOTAL][16][16];
__device__ unsigned long long g_top[T_TOTAL][16];
__device__ unsigned g_rel[T_TOTAL][32];
// scan_new tree: 1024 -> 64 -> 4 -> 1, fan-out to 64 group-release words
__device__ unsigned long long g_n1[T_TOTAL][64][16];
__device__ unsigned long long g_n2[T_TOTAL][4][16];
__device__ unsigned long long g_n3[T_TOTAL][16];
__device__ unsigned g_relg[T_TOTAL][64][32];   // [s][group][0]: total+1

__device__ __forceinline__ unsigned f2key(float f) {
    unsigned b = __float_as_uint(f);
    return b ^ ((unsigned)(((int)b) >> 31) | 0x80000000u);
}
__device__ __forceinline__ float key2f(unsigned k) {
    unsigned b = (k & 0x80000000u) ? (k ^ 0x80000000u) : ~k;
    return __uint_as_float(b);
}

// Exact reference bin: ((t-tmin)/(tmax-tmin))*(10-1e-6), trunc, clip.
__device__ __forceinline__ int event_bin_t(float tv, float tmin, float tmax) {
#pragma clang fp contract(off)
    float tn;
    if (tmax > tmin) tn = (tv - tmin) / (tmax - tmin) * (float)(10.0 - 1e-6);
    else tn = 0.0f;
    int ti = (int)tn;
    return ti < 0 ? 0 : (ti > T_EVT - 1 ? T_EVT - 1 : ti);
}
__device__ __forceinline__ int event_pixel(int xi, int yi, int ci) {
    xi = xi < 0 ? 0 : (xi > WW - 1 ? WW - 1 : xi);
    yi = yi < 0 ? 0 : (yi > HH - 1 ? HH - 1 : yi);
    return ci * (HH * WW) + yi * WW + xi;
}

// init_kernel: FALLBACK PATH ONLY.
__global__ void init_kernel() {
    const int gtid = blockIdx.x * blockDim.x + threadIdx.x;
    const int gs = gridDim.x * blockDim.x;
    if (gtid == 0) { g_minkey = 0xFFFFFFFFu; g_maxkey = 0u; }
    unsigned long long* a = &g_grp[0][0][0];
    for (int i = gtid; i < T_TOTAL * 16 * 16; i += gs) a[i] = 0ull;
    unsigned long long* b = &g_top[0][0];
    for (int i = gtid; i < T_TOTAL * 16; i += gs) b[i] = 0ull;
    unsigned* c = &g_rel[0][0];
    for (int i = gtid; i < T_TOTAL * 32; i += gs) c[i] = 0u;
}

// ======================= shared: t min/max (fallback path) ==============
__device__ __forceinline__ void minmax_body(const float* __restrict__ t, int n,
                                            int gtid, int gstride) {
    unsigned mn = 0xFFFFFFFFu, mx = 0u;
    const int n4 = n >> 2;
    const float4* t4 = (const float4*)t;
    for (int i = gtid; i < n4; i += gstride) {
        float4 tv = t4[i];
        unsigned k0 = f2key(tv.x), k1 = f2key(tv.y);
        unsigned k2 = f2key(tv.z), k3 = f2key(tv.w);
        unsigned a = k0 < k1 ? k0 : k1, b = k2 < k3 ? k2 : k3;
        unsigned c = a < b ? a : b;
        mn = mn < c ? mn : c;
        a = k0 > k1 ? k0 : k1; b = k2 > k3 ? k2 : k3;
        c = a > b ? a : b;
        mx = mx > c ? mx : c;
    }
    for (int i = (n4 << 2) + gtid; i < n; i += gstride) {
        unsigned k = f2key(t[i]);
        mn = mn < k ? mn : k;
        mx = mx > k ? mx : k;
    }
    for (int off = 32; off > 0; off >>= 1) {
        unsigned omn = (unsigned)__shfl_down((int)mn, off, 64);
        unsigned omx = (unsigned)__shfl_down((int)mx, off, 64);
        mn = mn < omn ? mn : omn;
        mx = mx > omx ? mx : omx;
    }
    __shared__ unsigned smn[16], smx[16];
    int lane = threadIdx.x & 63, wv = threadIdx.x >> 6;
    if (lane == 0) { smn[wv] = mn; smx[wv] = mx; }
    __syncthreads();
    if (threadIdx.x == 0) {
        int nw = blockDim.x >> 6;
        for (int i = 1; i < nw; ++i) {
            mn = mn < smn[i] ? mn : smn[i];
            mx = mx > smx[i] ? mx : smx[i];
        }
        atomicMin(&g_minkey, mn);
        atomicMax(&g_maxkey, mx);
    }
}

__global__ void minmax_zero_kernel(const float* __restrict__ t, int n,
                                   uint4* __restrict__ hist16v) {
    const int gtid = blockIdx.x * blockDim.x + threadIdx.x;
    const int gstride = gridDim.x * blockDim.x;
    const uint4 z = make_uint4(0u, 0u, 0u, 0u);
    const int nz = T_EVT * FRAME / 8;
    for (int i = gtid; i < nz; i += gstride) hist16v[i] = z;
    minmax_body(t, n, gtid, gstride);
}

// ======================= new path (R21) =================================
// minmax_ws: standalone t min/max into ws (zeroed by hipMemsetAsync).
// Inverted-key trick: mmx[0] accumulates max f2key (-> tmax); mmx[32]
// accumulates max ~f2key (-> tmin = key2f(~mmx[32])). Both init to 0, so a
// single memset suffices. mn/mx words 128 B apart (separate lines).
__global__ __launch_bounds__(MMTHR) void minmax_ws_kernel(
        const float* __restrict__ t, int n, unsigned* __restrict__ mmx) {
    const int gtid = blockIdx.x * blockDim.x + threadIdx.x;
    const int gstride = gridDim.x * blockDim.x;
    unsigned mx = 0u, imn = 0u;   // imn = max of ~key
    const int n4 = n >> 2;
    const float4* t4 = (const float4*)t;
    for (int i = gtid; i < n4; i += gstride) {
        float4 tv = t4[i];
        unsigned k0 = f2key(tv.x), k1 = f2key(tv.y);
        unsigned k2 = f2key(tv.z), k3 = f2key(tv.w);
        unsigned a = k0 > k1 ? k0 : k1, b = k2 > k3 ? k2 : k3;
        unsigned c = a > b ? a : b;
        mx = mx > c ? mx : c;
        unsigned i0 = ~k0, i1 = ~k1, i2 = ~k2, i3 = ~k3;
        a = i0 > i1 ? i0 : i1; b = i2 > i3 ? i2 : i3;
        c = a > b ? a : b;
        imn = imn > c ? imn : c;
    }
    for (int i = (n4 << 2) + gtid; i < n; i += gstride) {
        unsigned k = f2key(t[i]);
        mx = mx > k ? mx : k;
        unsigned ik = ~k;
        imn = imn > ik ? imn : ik;
    }
    for (int off = 32; off > 0; off >>= 1) {
        unsigned omx = (unsigned)__shfl_down((int)mx, off, 64);
        unsigned oim = (unsigned)__shfl_down((int)imn, off, 64);
        mx = mx > omx ? mx : omx;
        imn = imn > oim ? imn : oim;
    }
    __shared__ unsigned smx[MMTHR / 64], sim[MMTHR / 64];
    const int lane = threadIdx.x & 63, wv = threadIdx.x >> 6;
    if (lane == 0) { smx[wv] = mx; sim[wv] = imn; }
    __syncthreads();
    if (threadIdx.x == 0) {
#pragma unroll
        for (int i = 1; i < MMTHR / 64; ++i) {
            mx = mx > smx[i] ? mx : smx[i];
            imn = imn > sim[i] ? imn : sim[i];
        }
        atomicMax(&mmx[0], mx);
        atomicMax(&mmx[32], imn);
    }
}

// passAB: the whole sort in ONE kernel, no global prefix needed.
// seg layout is [chunk][bucket]: block bid LDS-counting-sorts its chunk
// (proven R17/R19 machinery) and writes it to its OWN contiguous region
// seg[bid*chunk .. bid*chunk+m) -- flush is a linear coalesced copy, no
// per-element base lookup. mat[bid][j] = (local_excl:16 | count:16) tells
// scan_new where bucket j's run lives inside the region. Eliminates keys
// (16 MB w + 16 MB r), passB, offsets kernel, and 2 launches.
__global__ __launch_bounds__(RTHR) void passAB_kernel(
        const int* __restrict__ x, const int* __restrict__ y,
        const int* __restrict__ p, const float* __restrict__ t,
        const unsigned* __restrict__ mmx,
        unsigned* __restrict__ mat, unsigned short* __restrict__ seg, int n) {
    __shared__ unsigned cnt[NBUCKET];    // counts -> rank counter
    __shared__ unsigned wt2[RTHR / 64];
    __shared__ unsigned short sorted[MAXM];  // 16 KB
    const int bid = blockIdx.x;
    const int j = threadIdx.x;           // RTHR == NBUCKET
    const int lane = j & 63, wv = j >> 6;
    const int gtid = bid * RTHR + j;
    const int gs = RBLK * RTHR;
    {   // zero scan_new's sync tree (kernel boundary = visibility for scan)
        unsigned long long* z1 = &g_n1[0][0][0];
        for (int i = gtid; i < T_TOTAL * 64 * 16; i += gs) z1[i] = 0ull;
        unsigned long long* z2 = &g_n2[0][0][0];
        for (int i = gtid; i < T_TOTAL * 4 * 16; i += gs) z2[i] = 0ull;
        unsigned long long* z3 = &g_n3[0][0];
        for (int i = gtid; i < T_TOTAL * 16; i += gs) z3[i] = 0ull;
        unsigned* z4 = &g_relg[0][0][0];
        for (int i = gtid; i < T_TOTAL * 64 * 32; i += gs) z4[i] = 0u;
    }
    cnt[j] = 0u;
    __syncthreads();
    const float tmax = key2f(mmx[0]);
    const float tmin = key2f(~mmx[32]);
    const int chunk = (((n + RBLK - 1) / RBLK) + 3) & ~3;   // mult of 4
    const int s0 = bid * chunk;
    const int s1 = min(n, s0 + chunk);
    const int m = s1 - s0;               // <= MAXM (launcher-guarded)

    // phase 1: vectorized read, records in registers, count buckets
    unsigned rec[EPT];
#pragma unroll
    for (int k = 0; k < EPT / 4; ++k) {
        const int ibase = s0 + ((k * RTHR + j) << 2);
#pragma unroll
        for (int e = 0; e < 4; ++e) rec[k * 4 + e] = 0xFFFFFFFFu;
        if (ibase + 4 <= s1) {
            int4 xv = *(const int4*)(x + ibase);
            int4 yv = *(const int4*)(y + ibase);
            int4 pv = *(const int4*)(p + ibase);
            float4 tv = *(const float4*)(t + ibase);
            int pxs[4] = { event_pixel(xv.x, yv.x, pv.x),
                           event_pixel(xv.y, yv.y, pv.y),
                           event_pixel(xv.z, yv.z, pv.z),
                           event_pixel(xv.w, yv.w, pv.w) };
            float ts[4] = { tv.x, tv.y, tv.z, tv.w };
#pragma unroll
            for (int e = 0; e < 4; ++e) {
                int pix = pxs[e];
                int ti = event_bin_t(ts[e], tmin, tmax);
                int bkt = pix / PIXB;
                int lb = ti * PIXB + (pix - bkt * PIXB);   // < 18000
                rec[k * 4 + e] = ((unsigned)bkt << 16) | (unsigned)lb;
                atomicAdd(&cnt[bkt], 1u);
            }
        } else if (ibase < s1) {
            for (int e = 0; e < 4; ++e) {
                int i = ibase + e;
                if (i < s1) {
                    int pix = event_pixel(x[i], y[i], p[i]);
                    int ti = event_bin_t(t[i], tmin, tmax);
                    int bkt = pix / PIXB;
                    int lb = ti * PIXB + (pix - bkt * PIXB);
                    rec[k * 4 + e] = ((unsigned)bkt << 16) | (unsigned)lb;
                    atomicAdd(&cnt[bkt], 1u);
                }
            }
        }
    }
    __syncthreads();
    // phase 2: block scan of counts -> local exclusive prefix; pack mat.
    {
        unsigned v = cnt[j];
        unsigned incl = v;
        for (int off = 1; off < 64; off <<= 1) {
            unsigned o = (unsigned)__shfl_up((int)incl, off, 64);
            if (lane >= off) incl += o;
        }
        if (lane == 63) wt2[wv] = incl;
        __syncthreads();
        if (j == 0) {
            unsigned run = 0;
#pragma unroll
            for (int k = 0; k < RTHR / 64; ++k) { unsigned tmp = wt2[k]; wt2[k] = run; run += tmp; }
        }
        __syncthreads();
        unsigned ex = incl - v + wt2[wv];   // < 8192, fits 16 bits
        mat[bid * NBUCKET + j] = (ex << 16) | v;
        cnt[j] = ex;                        // own slot only: no hazard
    }
    __syncthreads();
    // phase 3: rank from registers -> LDS sorted array
#pragma unroll
    for (int k = 0; k < EPT; ++k) {
        unsigned r0 = rec[k];
        if (r0 != 0xFFFFFFFFu) {
            unsigned bkt = r0 >> 16;
            unsigned r = atomicAdd(&cnt[bkt], 1u);
            sorted[r] = (unsigned short)(r0 & 0xFFFFu);
        }
    }
    __syncthreads();
    // phase 4: linear coalesced flush into this block's own seg region
    unsigned short* segb = seg + (size_t)bid * (size_t)chunk;
    for (int i = j; i < m; i += RTHR) segb[i] = sorted[i];
}

// Cooperative scan, 1024 blocks x 256 thr (R9-R17 core, byte-identical
// barrier/LIF machinery). R21: hist-build reads 512 per-chunk runs located
// via mat[r][b] instead of one contiguous segment.
__global__ __launch_bounds__(STHR, 4) void scan_new(float* __restrict__ out,
                                                    const unsigned short* __restrict__ seg,
                                                    const unsigned* __restrict__ mat,
                                                    int n) {
#pragma clang fp contract(off)
    const float decay = (float)0.9048374180359595;  // float32(exp(-1/10))
    const int tid = threadIdx.x;
    const int lane = tid & 63;
    const int b = blockIdx.x;
    const int pix0 = b * PIXB;

    __shared__ alignas(16) unsigned lds_hist[HIST_W];
    __shared__ unsigned runw[RBLK];
    __shared__ unsigned lds_arr[T_TOTAL];
    __shared__ unsigned lds_tot[T_TOTAL];

    for (int i = tid; i < HIST_W; i += STHR) lds_hist[i] = 0u;
    for (int r = tid; r < RBLK; r += STHR) runw[r] = mat[r * NBUCKET + b];
    if (tid < T_TOTAL) { lds_arr[tid] = 0u; lds_tot[tid] = 0u; }
    __syncthreads();

    {
        const int chunk = (((n + RBLK - 1) / RBLK) + 3) & ~3;
        for (int r = tid; r < RBLK; r += STHR) {
            unsigned w = runw[r];
            unsigned c = w & 0xFFFFu;
            const unsigned short* sp = seg + (size_t)r * (size_t)chunk + (w >> 16);
            for (unsigned k = 0; k < c; ++k) {
                unsigned lb = sp[k];
                atomicAdd(&lds_hist[lb >> 1], 1u << ((lb & 1u) << 4));
            }
        }
    }
    __syncthreads();

    const bool has1 = tid < (NGROUP4 - STHR);
    float4 mem0 = make_float4(0.f, 0.f, 0.f, 0.f);
    float4 mem1 = make_float4(0.f, 0.f, 0.f, 0.f);
    float thr = 1.0f;

    float4 f0, f1;
    {
        uint2 w01 = *(const uint2*)&lds_hist[tid << 1];
        f0 = make_float4((float)(w01.x & 0xFFFFu), (float)(w01.x >> 16),
                         (float)(w01.y & 0xFFFFu), (float)(w01.y >> 16));
        if (has1) {
            uint2 v = *(const uint2*)&lds_hist[(tid + STHR) << 1];
            f1 = make_float4((float)(v.x & 0xFFFFu), (float)(v.x >> 16),
                             (float)(v.y & 0xFFFFu), (float)(v.y >> 16));
        } else f1 = make_float4(0.f, 0.f, 0.f, 0.f);
    }

    for (int s = 0;; ++s) {
        float* ob = out + (size_t)s * FRAME + pix0;
        int cnt = 0;

        {
            float4 m, spk;
            m.x = mem0.x + f0.x;
            m.y = mem0.y + f0.y;
            m.z = mem0.z + f0.z;
            m.w = mem0.w + f0.w;
            spk.x = (m.x >= thr) ? 1.0f : 0.0f;
            spk.y = (m.y >= thr) ? 1.0f : 0.0f;
            spk.z = (m.z >= thr) ? 1.0f : 0.0f;
            spk.w = (m.w >= thr) ? 1.0f : 0.0f;
            ((float4*)ob)[tid] = spk;
            mem0.x = m.x - spk.x * thr;
            mem0.y = m.y - spk.y * thr;
            mem0.z = m.z - spk.z * thr;
            mem0.w = m.w - spk.w * thr;
            cnt += (int)spk.x + (int)spk.y + (int)spk.z + (int)spk.w;
        }
        if (has1) {
            int g = tid + STHR;
            float4 m, spk;
            m.x = mem1.x + f1.x;
            m.y = mem1.y + f1.y;
            m.z = mem1.z + f1.z;
            m.w = mem1.w + f1.w;
            spk.x = (m.x >= thr) ? 1.0f : 0.0f;
            spk.y = (m.y >= thr) ? 1.0f : 0.0f;
            spk.z = (m.z >= thr) ? 1.0f : 0.0f;
            spk.w = (m.w >= thr) ? 1.0f : 0.0f;
            ((float4*)ob)[g] = spk;
            mem1.x = m.x - spk.x * thr;
            mem1.y = m.y - spk.y * thr;
            mem1.z = m.z - spk.z * thr;
            mem1.w = m.w - spk.w * thr;
            cnt += (int)spk.x + (int)spk.y + (int)spk.z + (int)spk.w;
        }

        if (s == T_TOTAL - 1) break;

        for (int off = 32; off > 0; off >>= 1) cnt += __shfl_down(cnt, off, 64);

        // ---- arrive phase (leader only; no polling yet) ----
        bool last = false;
        const int g1 = b >> 4;
        if (lane == 0) {
            unsigned old = __hip_atomic_fetch_add(&lds_arr[s],
                               (unsigned)cnt + (1u << 16),
                               __ATOMIC_RELAXED, __HIP_MEMORY_SCOPE_WORKGROUP);
            if ((old >> 16) == SWPB - 1) {
                last = true;
                unsigned bc = (old + (unsigned)cnt) & 0xFFFFu;
                unsigned long long a1 = __hip_atomic_fetch_add(
                    &g_n1[s][g1][0], (unsigned long long)bc + ARRIVE64,
                    __ATOMIC_RELAXED, __HIP_MEMORY_SCOPE_AGENT);
                if ((unsigned)(a1 >> 32) == 15u) {
                    unsigned c1 = (unsigned)a1 + bc;
                    const int g2 = g1 >> 4;
                    unsigned long long a2 = __hip_atomic_fetch_add(
                        &g_n2[s][g2][0], (unsigned long long)c1 + ARRIVE64,
                        __ATOMIC_RELAXED, __HIP_MEMORY_SCOPE_AGENT);
                    if ((unsigned)(a2 >> 32) == 15u) {
                        unsigned c2 = (unsigned)a2 + c1;
                        unsigned long long a3 = __hip_atomic_fetch_add(
                            &g_n3[s][0], (unsigned long long)c2 + ARRIVE64,
                            __ATOMIC_RELAXED, __HIP_MEMORY_SCOPE_AGENT);
                        if ((unsigned)(a3 >> 32) == 3u) {
                            unsigned tot = (unsigned)a3 + c2;
                            for (int g = 0; g < 64; ++g)
                                __hip_atomic_store(&g_relg[s][g][0], tot + 1u,
                                    __ATOMIC_RELAXED, __HIP_MEMORY_SCOPE_AGENT);
                        }
                    }
                }
            }
        }

        // ---- prefetch next frame + pre-decay, under the barrier shadow ----
        {
            const int sn = s + 1;
            if (sn < T_EVT) {
                uint2 w01 = *(const uint2*)&lds_hist[sn * 900 + (tid << 1)];
                f0 = make_float4((float)(w01.x & 0xFFFFu), (float)(w01.x >> 16),
                                 (float)(w01.y & 0xFFFFu), (float)(w01.y >> 16));
                if (has1) {
                    uint2 v = *(const uint2*)&lds_hist[sn * 900 + ((tid + STHR) << 1)];
                    f1 = make_float4((float)(v.x & 0xFFFFu), (float)(v.x >> 16),
                                     (float)(v.y & 0xFFFFu), (float)(v.y >> 16));
                }
            } else {
                f0 = make_float4(0.f, 0.f, 0.f, 0.f);
                f1 = make_float4(0.f, 0.f, 0.f, 0.f);
            }
            mem0.x = mem0.x * decay; mem0.y = mem0.y * decay;
            mem0.z = mem0.z * decay; mem0.w = mem0.w * decay;
            mem1.x = mem1.x * decay; mem1.y = mem1.y * decay;
            mem1.z = mem1.z * decay; mem1.w = mem1.w * decay;
        }
        __builtin_amdgcn_sched_barrier(0);   // keep prefetch before the poll

        // ---- poll phase ----
        unsigned total = 0u;
        if (lane == 0) {
            unsigned f;
            if (last) {
                do {
                    __builtin_amdgcn_s_sleep(1);
                    f = __hip_atomic_load(&g_relg[s][g1][0], __ATOMIC_RELAXED,
                                          __HIP_MEMORY_SCOPE_AGENT);
                } while (f == 0u);
                total = f - 1u;
                __hip_atomic_store(&lds_tot[s], f,
                                   __ATOMIC_RELAXED, __HIP_MEMORY_SCOPE_WORKGROUP);
            } else {
                unsigned f2;
                do {
                    __builtin_amdgcn_s_sleep(1);
                    f2 = __hip_atomic_load(&lds_tot[s], __ATOMIC_RELAXED,
                                           __HIP_MEMORY_SCOPE_WORKGROUP);
                } while (f2 == 0u);
                total = f2 - 1u;
            }
        }
        total = (unsigned)__shfl((int)total, 0, 64);
        float rate = (float)total / 1843200.0f;
        thr = thr + 0.1f * (rate - 0.1f);
        thr = fminf(fmaxf(thr, 0.1f), 10.0f);
    }
}

// ======================= old (fallback) path =======================
__global__ void scatter_kernel(const int* __restrict__ x, const int* __restrict__ y,
                               const int* __restrict__ p, const float* __restrict__ t,
                               unsigned* __restrict__ hist32, int n) {
    int i = blockIdx.x * blockDim.x + threadIdx.x;
    if (i >= n) return;
    float tmin = key2f(g_minkey);
    float tmax = key2f(g_maxkey);
    int ti = event_bin_t(t[i], tmin, tmax);
    int pix = event_pixel(x[i], y[i], p[i]);
    size_t bidx = (size_t)ti * FRAME + pix;
    atomicAdd(hist32 + (bidx >> 1), 1u << ((bidx & 1) << 4));
}

__global__ __launch_bounds__(ONTHR) void scan_old(float* __restrict__ out) {
#pragma clang fp contract(off)
    const float decay = (float)0.9048374180359595;
    const int gtid = blockIdx.x * ONTHR + threadIdx.x;
    const int lane = threadIdx.x & 63;
    const uint2 uz2 = make_uint2(0u, 0u);
    float4 mem0 = make_float4(0.f, 0.f, 0.f, 0.f);
    float4 mem1 = make_float4(0.f, 0.f, 0.f, 0.f);
    const bool has1 = (gtid + ONT) < FRAME4;
    float thr = 1.0f;
    const uint2* hist2 = (const uint2*)(out + (size_t)T_EVT * FRAME);
    __shared__ unsigned lds_arr[T_TOTAL];
    __shared__ unsigned lds_tot[T_TOTAL];
    if (threadIdx.x < T_TOTAL) { lds_arr[threadIdx.x] = 0u; lds_tot[threadIdx.x] = 0u; }
    __syncthreads();
    uint2 u0 = hist2[gtid];
    uint2 u1 = has1 ? hist2[gtid + ONT] : uz2;
    for (int s = 0; s < T_TOTAL; ++s) {
        float4* o4 = (float4*)(out + (size_t)s * FRAME);
        int cnt = 0;
        {
            float4 m, spk;
            m.x = mem0.x * decay; m.x = m.x + (float)(u0.x & 0xFFFFu);
            m.y = mem0.y * decay; m.y = m.y + (float)(u0.x >> 16);
            m.z = mem0.z * decay; m.z = m.z + (float)(u0.y & 0xFFFFu);
            m.w = mem0.w * decay; m.w = m.w + (float)(u0.y >> 16);
            spk.x = (m.x >= thr) ? 1.0f : 0.0f;
            spk.y = (m.y >= thr) ? 1.0f : 0.0f;
            spk.z = (m.z >= thr) ? 1.0f : 0.0f;
            spk.w = (m.w >= thr) ? 1.0f : 0.0f;
            o4[gtid] = spk;
            mem0.x = m.x - spk.x * thr; mem0.y = m.y - spk.y * thr;
            mem0.z = m.z - spk.z * thr; mem0.w = m.w - spk.w * thr;
            cnt += (int)spk.x + (int)spk.y + (int)spk.z + (int)spk.w;
        }
        if (has1) {
            float4 m, spk;
            m.x = mem1.x * decay; m.x = m.x + (float)(u1.x & 0xFFFFu);
            m.y = mem1.y * decay; m.y = m.y + (float)(u1.x >> 16);
            m.z = mem1.z * decay; m.z = m.z + (float)(u1.y & 0xFFFFu);
            m.w = mem1.w * decay; m.w = m.w + (float)(u1.y >> 16);
            spk.x = (m.x >= thr) ? 1.0f : 0.0f;
            spk.y = (m.y >= thr) ? 1.0f : 0.0f;
            spk.z = (m.z >= thr) ? 1.0f : 0.0f;
            spk.w = (m.w >= thr) ? 1.0f : 0.0f;
            o4[gtid + ONT] = spk;
            mem1.x = m.x - spk.x * thr; mem1.y = m.y - spk.y * thr;
            mem1.z = m.z - spk.z * thr; mem1.w = m.w - spk.w * thr;
            cnt += (int)spk.x + (int)spk.y + (int)spk.z + (int)spk.w;
        }
        if (s + 1 < T_EVT) {
            const uint2* hn = hist2 + (size_t)(s + 1) * FRAME4;
            u0 = hn[gtid];
            u1 = has1 ? hn[gtid + ONT] : uz2;
        } else { u0 = uz2; u1 = uz2; }
        if (s == T_TOTAL - 1) break;
        for (int off = 32; off > 0; off >>= 1) cnt += __shfl_down(cnt, off, 64);
        unsigned total = 0u;
        if (lane == 0) {
            unsigned old = __hip_atomic_fetch_add(&lds_arr[s],
                               (unsigned)cnt + (1u << 16),
                               __ATOMIC_RELAXED, __HIP_MEMORY_SCOPE_WORKGROUP);
            if ((old >> 16) == ONWPB - 1) {
                unsigned bc = (old + (unsigned)cnt) & 0xFFFFu;
                const int gid = blockIdx.x >> 4;
                unsigned long long gold = __hip_atomic_fetch_add(
                    &g_grp[s][gid][0], (unsigned long long)bc + ARRIVE64,
                    __ATOMIC_RELAXED, __HIP_MEMORY_SCOPE_AGENT);
                if ((unsigned)(gold >> 32) == 15u) {
                    unsigned gc = (unsigned)gold + bc;
                    unsigned long long told = __hip_atomic_fetch_add(
                        &g_top[s][0], (unsigned long long)gc + ARRIVE64,
                        __ATOMIC_RELAXED, __HIP_MEMORY_SCOPE_AGENT);
                    if ((unsigned)(told >> 32) == 15u) {
                        unsigned tot = (unsigned)told + gc;
                        __hip_atomic_store(&g_rel[s][0], tot + 1u,
                                           __ATOMIC_RELAXED, __HIP_MEMORY_SCOPE_AGENT);
                    }
                }
                unsigned f;
                do {
                    __builtin_amdgcn_s_sleep(1);
                    f = __hip_atomic_load(&g_rel[s][0], __ATOMIC_RELAXED,
                                          __HIP_MEMORY_SCOPE_AGENT);
                } while (f == 0u);
                total = f - 1u;
                __hip_atomic_store(&lds_tot[s], f,
                                   __ATOMIC_RELAXED, __HIP_MEMORY_SCOPE_WORKGROUP);
            } else {
                unsigned f;
                do {
                    __builtin_amdgcn_s_sleep(1);
                    f = __hip_atomic_load(&lds_tot[s], __ATOMIC_RELAXED,
                                          __HIP_MEMORY_SCOPE_WORKGROUP);
                } while (f == 0u);
                total = f - 1u;
            }
        }
        total = (unsigned)__shfl((int)total, 0, 64);
        float rate = (float)total / 1843200.0f;
        thr = thr + 0.1f * (rate - 0.1f);
        thr = fminf(fmaxf(thr, 0.1f), 10.0f);
    }
}

extern "C" void kernel_launch(void* const* d_in, const int* in_sizes, int n_in,
                              void* d_out, int out_size, void* d_ws, size_t ws_size,
                              hipStream_t stream) {
    const int*   x = (const int*)d_in[0];
    const int*   y = (const int*)d_in[1];
    const int*   p = (const int*)d_in[2];
    const float* t = (const float*)d_in[3];
    float* out = (float*)d_out;
    const int n = in_sizes[0];

    const int chunk = (((n + RBLK - 1) / RBLK) + 3) & ~3;
    if (d_ws != nullptr && ws_size >= WS_NEED(chunk) && chunk <= MAXM && n >= 4) {
        unsigned* mat = (unsigned*)((char*)d_ws + MAT_OFF);
        unsigned* mmx = (unsigned*)((char*)d_ws + MMX_OFF);
        unsigned short* seg = (unsigned short*)((char*)d_ws + KEY_OFF);

        // zero the minmax accumulators (capture-safe async memset, 256 B)
        hipMemsetAsync(mmx, 0, 256, stream);
        minmax_ws_kernel<<<MMBLK, MMTHR, 0, stream>>>(t, n, mmx);
        passAB_kernel<<<RBLK, RTHR, 0, stream>>>(x, y, p, t, mmx, mat, seg, n);

        dim3 g(SBLK), b(STHR);
        void* args[] = { (void*)&out, (void*)&seg, (void*)&mat, (void*)&n };
        hipLaunchCooperativeKernel((void*)scan_new, g, b, args, 0, stream);
    } else {
        init_kernel<<<64, 256, 0, stream>>>();
        unsigned* hist32 = (unsigned*)(out + (size_t)T_EVT * FRAME);
        minmax_zero_kernel<<<1024, 256, 0, stream>>>(t, n, (uint4*)hist32);
        scatter_kernel<<<(n + 255) / 256, 256, 0, stream>>>(x, y, p, t, hist32, n);
        dim3 g(ONBLK), b(ONTHR);
        void* args[] = { (void*)&out };
        hipLaunchCooperativeKernel((void*)scan_old, g, b, args, 0, stream);
    }
}

// Round 10
// 305.834 us; speedup vs baseline: 1.0159x; 1.0061x over previous
//
#include <hip/hip_runtime.h>
#include <cstddef>

#define HH 720
#define WW 1280
#define FRAME 1843200            // 2*720*1280
#define FRAME4 460800            // FRAME/4
#define T_EVT 10
#define T_TOTAL 20
#define ARRIVE64 (1ULL << 32)

// ---------- old (fallback) path config ----------
#define ONBLK 256
#define ONTHR 1024
#define ONWPB 16
#define ONT (ONBLK * ONTHR)

// ---------- new path config ----------
#define SBLK 1024                // scan blocks (4 per CU)
#define STHR 256                 // scan threads per block (4 waves)
#define SWPB 4
#define PIXB 1800                // pixels per scan block
#define NGROUP4 450              // float4 groups per block (1800/4)
#define HIST_W 9000              // LDS hist words (18000 u16)
#define RBLK 512                 // passAB blocks / mat rows
#define RTHR 1024
#define NBUCKET 1024
#define EPT 8                    // records/thread (8*1024=8192 >= chunk4)
#define MAXM (EPT * RTHR)
#define MMBLK 128                // minmax kernel blocks
#define MMTHR 1024

// ws layout (bytes), all 256-aligned.
// seg is [chunk]-local, RBLK*chunk4 u16 entries at KEY_OFF.
#define MAT_OFF   0u                           // u32[1024*512] = 2 MB (R22: [bucket][block])
#define MMX_OFF   (512u * 1024u * 4u)          // (unused since R22, kept for layout)
#define KEY_OFF   (MMX_OFF + 4096u)
#define WS_NEED(chunk) ((size_t)KEY_OFF + 2ull * RBLK * (size_t)(chunk) + 256ull)

// Persistent device globals.
__device__ unsigned g_minkey;
__device__ unsigned g_maxkey;
// R22: minmax per-block partials (plain stores; all 128 blocks overwrite
// every run, reduced by every passAB block in its prologue -- no init, no
// atomics, no memset; kernel boundary = visibility, the proven mechanism).
__device__ unsigned g_mm_mx[MMBLK];
__device__ unsigned g_mm_imn[MMBLK];
// old-path tree (R8, proven)
__device__ unsigned long long g_grp[T_TOTAL][16][16];
__device__ unsigned long long g_top[T_TOTAL][16];
__device__ unsigned g_rel[T_TOTAL][32];
// scan_new tree: 1024 -> 64 -> 4 -> 1, fan-out to 64 group-release words
__device__ unsigned long long g_n1[T_TOTAL][64][16];
__device__ unsigned long long g_n2[T_TOTAL][4][16];
__device__ unsigned long long g_n3[T_TOTAL][16];
__device__ unsigned g_relg[T_TOTAL][64][32];   // [s][group][0]: total+1

__device__ __forceinline__ unsigned f2key(float f) {
    unsigned b = __float_as_uint(f);
    return b ^ ((unsigned)(((int)b) >> 31) | 0x80000000u);
}
__device__ __forceinline__ float key2f(unsigned k) {
    unsigned b = (k & 0x80000000u) ? (k ^ 0x80000000u) : ~k;
    return __uint_as_float(b);
}

// Exact reference bin: ((t-tmin)/(tmax-tmin))*(10-1e-6), trunc, clip.
__device__ __forceinline__ int event_bin_t(float tv, float tmin, float tmax) {
#pragma clang fp contract(off)
    float tn;
    if (tmax > tmin) tn = (tv - tmin) / (tmax - tmin) * (float)(10.0 - 1e-6);
    else tn = 0.0f;
    int ti = (int)tn;
    return ti < 0 ? 0 : (ti > T_EVT - 1 ? T_EVT - 1 : ti);
}
__device__ __forceinline__ int event_pixel(int xi, int yi, int ci) {
    xi = xi < 0 ? 0 : (xi > WW - 1 ? WW - 1 : xi);
    yi = yi < 0 ? 0 : (yi > HH - 1 ? HH - 1 : yi);
    return ci * (HH * WW) + yi * WW + xi;
}

// init_kernel: FALLBACK PATH ONLY.
__global__ void init_kernel() {
    const int gtid = blockIdx.x * blockDim.x + threadIdx.x;
    const int gs = gridDim.x * blockDim.x;
    if (gtid == 0) { g_minkey = 0xFFFFFFFFu; g_maxkey = 0u; }
    unsigned long long* a = &g_grp[0][0][0];
    for (int i = gtid; i < T_TOTAL * 16 * 16; i += gs) a[i] = 0ull;
    unsigned long long* b = &g_top[0][0];
    for (int i = gtid; i < T_TOTAL * 16; i += gs) b[i] = 0ull;
    unsigned* c = &g_rel[0][0];
    for (int i = gtid; i < T_TOTAL * 32; i += gs) c[i] = 0u;
}

// ======================= shared: t min/max (fallback path) ==============
__device__ __forceinline__ void minmax_body(const float* __restrict__ t, int n,
                                            int gtid, int gstride) {
    unsigned mn = 0xFFFFFFFFu, mx = 0u;
    const int n4 = n >> 2;
    const float4* t4 = (const float4*)t;
    for (int i = gtid; i < n4; i += gstride) {
        float4 tv = t4[i];
        unsigned k0 = f2key(tv.x), k1 = f2key(tv.y);
        unsigned k2 = f2key(tv.z), k3 = f2key(tv.w);
        unsigned a = k0 < k1 ? k0 : k1, b = k2 < k3 ? k2 : k3;
        unsigned c = a < b ? a : b;
        mn = mn < c ? mn : c;
        a = k0 > k1 ? k0 : k1; b = k2 > k3 ? k2 : k3;
        c = a > b ? a : b;
        mx = mx > c ? mx : c;
    }
    for (int i = (n4 << 2) + gtid; i < n; i += gstride) {
        unsigned k = f2key(t[i]);
        mn = mn < k ? mn : k;
        mx = mx > k ? mx : k;
    }
    for (int off = 32; off > 0; off >>= 1) {
        unsigned omn = (unsigned)__shfl_down((int)mn, off, 64);
        unsigned omx = (unsigned)__shfl_down((int)mx, off, 64);
        mn = mn < omn ? mn : omn;
        mx = mx > omx ? mx : omx;
    }
    __shared__ unsigned smn[16], smx[16];
    int lane = threadIdx.x & 63, wv = threadIdx.x >> 6;
    if (lane == 0) { smn[wv] = mn; smx[wv] = mx; }
    __syncthreads();
    if (threadIdx.x == 0) {
        int nw = blockDim.x >> 6;
        for (int i = 1; i < nw; ++i) {
            mn = mn < smn[i] ? mn : smn[i];
            mx = mx > smx[i] ? mx : smx[i];
        }
        atomicMin(&g_minkey, mn);
        atomicMax(&g_maxkey, mx);
    }
}

__global__ void minmax_zero_kernel(const float* __restrict__ t, int n,
                                   uint4* __restrict__ hist16v) {
    const int gtid = blockIdx.x * blockDim.x + threadIdx.x;
    const int gstride = gridDim.x * blockDim.x;
    const uint4 z = make_uint4(0u, 0u, 0u, 0u);
    const int nz = T_EVT * FRAME / 8;
    for (int i = gtid; i < nz; i += gstride) hist16v[i] = z;
    minmax_body(t, n, gtid, gstride);
}

// ======================= new path (R21/R22) =============================
// minmax_ws: t min/max -> 128 per-block partials (plain stores, no init).
// Inverted-key trick: g_mm_mx[b] = block max f2key (-> tmax);
// g_mm_imn[b] = block max ~f2key (-> tmin). Identity 0 for both.
__global__ __launch_bounds__(MMTHR) void minmax_ws_kernel(
        const float* __restrict__ t, int n) {
    const int gtid = blockIdx.x * blockDim.x + threadIdx.x;
    const int gstride = gridDim.x * blockDim.x;
    unsigned mx = 0u, imn = 0u;   // imn = max of ~key
    const int n4 = n >> 2;
    const float4* t4 = (const float4*)t;
    for (int i = gtid; i < n4; i += gstride) {
        float4 tv = t4[i];
        unsigned k0 = f2key(tv.x), k1 = f2key(tv.y);
        unsigned k2 = f2key(tv.z), k3 = f2key(tv.w);
        unsigned a = k0 > k1 ? k0 : k1, b = k2 > k3 ? k2 : k3;
        unsigned c = a > b ? a : b;
        mx = mx > c ? mx : c;
        unsigned i0 = ~k0, i1 = ~k1, i2 = ~k2, i3 = ~k3;
        a = i0 > i1 ? i0 : i1; b = i2 > i3 ? i2 : i3;
        c = a > b ? a : b;
        imn = imn > c ? imn : c;
    }
    for (int i = (n4 << 2) + gtid; i < n; i += gstride) {
        unsigned k = f2key(t[i]);
        mx = mx > k ? mx : k;
        unsigned ik = ~k;
        imn = imn > ik ? imn : ik;
    }
    for (int off = 32; off > 0; off >>= 1) {
        unsigned omx = (unsigned)__shfl_down((int)mx, off, 64);
        unsigned oim = (unsigned)__shfl_down((int)imn, off, 64);
        mx = mx > omx ? mx : omx;
        imn = imn > oim ? imn : oim;
    }
    __shared__ unsigned smx[MMTHR / 64], sim[MMTHR / 64];
    const int lane = threadIdx.x & 63, wv = threadIdx.x >> 6;
    if (lane == 0) { smx[wv] = mx; sim[wv] = imn; }
    __syncthreads();
    if (threadIdx.x == 0) {
#pragma unroll
        for (int i = 1; i < MMTHR / 64; ++i) {
            mx = mx > smx[i] ? mx : smx[i];
            imn = imn > sim[i] ? imn : sim[i];
        }
        g_mm_mx[blockIdx.x] = mx;
        g_mm_imn[blockIdx.x] = imn;
    }
}

// passAB: the whole sort in ONE kernel; seg is [chunk]-local, mat is
// TRANSPOSED [bucket][block] (R22) so scan_new's run-table read is one
// contiguous 2 KB row. Prologue: wave 0 reduces the 128 minmax partials.
__global__ __launch_bounds__(RTHR) void passAB_kernel(
        const int* __restrict__ x, const int* __restrict__ y,
        const int* __restrict__ p, const float* __restrict__ t,
        unsigned* __restrict__ mat, unsigned short* __restrict__ seg, int n) {
    __shared__ unsigned cnt[NBUCKET];    // counts -> rank counter
    __shared__ unsigned wt2[RTHR / 64];
    __shared__ float s_tmin, s_tmax;
    __shared__ unsigned short sorted[MAXM];  // 16 KB
    const int bid = blockIdx.x;
    const int j = threadIdx.x;           // RTHR == NBUCKET
    const int lane = j & 63, wv = j >> 6;
    const int gtid = bid * RTHR + j;
    const int gs = RBLK * RTHR;
    {   // zero scan_new's sync tree (kernel boundary = visibility for scan)
        unsigned long long* z1 = &g_n1[0][0][0];
        for (int i = gtid; i < T_TOTAL * 64 * 16; i += gs) z1[i] = 0ull;
        unsigned long long* z2 = &g_n2[0][0][0];
        for (int i = gtid; i < T_TOTAL * 4 * 16; i += gs) z2[i] = 0ull;
        unsigned long long* z3 = &g_n3[0][0];
        for (int i = gtid; i < T_TOTAL * 16; i += gs) z3[i] = 0ull;
        unsigned* z4 = &g_relg[0][0][0];
        for (int i = gtid; i < T_TOTAL * 64 * 32; i += gs) z4[i] = 0u;
    }
    cnt[j] = 0u;
    if (j < 64) {    // wave 0: reduce 128 minmax partials (L2-hit, 512 B)
        unsigned mxa = g_mm_mx[j], mxb = g_mm_mx[j + 64];
        unsigned ima = g_mm_imn[j], imb = g_mm_imn[j + 64];
        unsigned mx = mxa > mxb ? mxa : mxb;
        unsigned im = ima > imb ? ima : imb;
        for (int off = 32; off > 0; off >>= 1) {
            unsigned omx = (unsigned)__shfl_down((int)mx, off, 64);
            unsigned oim = (unsigned)__shfl_down((int)im, off, 64);
            mx = mx > omx ? mx : omx;
            im = im > oim ? im : oim;
        }
        if (j == 0) { s_tmax = key2f(mx); s_tmin = key2f(~im); }
    }
    __syncthreads();
    const float tmax = s_tmax;
    const float tmin = s_tmin;
    const int chunk = (((n + RBLK - 1) / RBLK) + 3) & ~3;   // mult of 4
    const int s0 = bid * chunk;
    const int s1 = min(n, s0 + chunk);
    const int m = s1 - s0;               // <= MAXM (launcher-guarded)

    // phase 1: vectorized read, records in registers, count buckets
    unsigned rec[EPT];
#pragma unroll
    for (int k = 0; k < EPT / 4; ++k) {
        const int ibase = s0 + ((k * RTHR + j) << 2);
#pragma unroll
        for (int e = 0; e < 4; ++e) rec[k * 4 + e] = 0xFFFFFFFFu;
        if (ibase + 4 <= s1) {
            int4 xv = *(const int4*)(x + ibase);
            int4 yv = *(const int4*)(y + ibase);
            int4 pv = *(const int4*)(p + ibase);
            float4 tv = *(const float4*)(t + ibase);
            int pxs[4] = { event_pixel(xv.x, yv.x, pv.x),
                           event_pixel(xv.y, yv.y, pv.y),
                           event_pixel(xv.z, yv.z, pv.z),
                           event_pixel(xv.w, yv.w, pv.w) };
            float ts[4] = { tv.x, tv.y, tv.z, tv.w };
#pragma unroll
            for (int e = 0; e < 4; ++e) {
                int pix = pxs[e];
                int ti = event_bin_t(ts[e], tmin, tmax);
                int bkt = pix / PIXB;
                int lb = ti * PIXB + (pix - bkt * PIXB);   // < 18000
                rec[k * 4 + e] = ((unsigned)bkt << 16) | (unsigned)lb;
                atomicAdd(&cnt[bkt], 1u);
            }
        } else if (ibase < s1) {
            for (int e = 0; e < 4; ++e) {
                int i = ibase + e;
                if (i < s1) {
                    int pix = event_pixel(x[i], y[i], p[i]);
                    int ti = event_bin_t(t[i], tmin, tmax);
                    int bkt = pix / PIXB;
                    int lb = ti * PIXB + (pix - bkt * PIXB);
                    rec[k * 4 + e] = ((unsigned)bkt << 16) | (unsigned)lb;
                    atomicAdd(&cnt[bkt], 1u);
                }
            }
        }
    }
    __syncthreads();
    // phase 2: block scan of counts -> local exclusive prefix; pack mat.
    {
        unsigned v = cnt[j];
        unsigned incl = v;
        for (int off = 1; off < 64; off <<= 1) {
            unsigned o = (unsigned)__shfl_up((int)incl, off, 64);
            if (lane >= off) incl += o;
        }
        if (lane == 63) wt2[wv] = incl;
        __syncthreads();
        if (j == 0) {
            unsigned run = 0;
#pragma unroll
            for (int k = 0; k < RTHR / 64; ++k) { unsigned tmp = wt2[k]; wt2[k] = run; run += tmp; }
        }
        __syncthreads();
        unsigned ex = incl - v + wt2[wv];   // < 8192, fits 16 bits
        mat[j * RBLK + bid] = (ex << 16) | v;   // R22: transposed
        cnt[j] = ex;                        // own slot only: no hazard
    }
    __syncthreads();
    // phase 3: rank from registers -> LDS sorted array
#pragma unroll
    for (int k = 0; k < EPT; ++k) {
        unsigned r0 = rec[k];
        if (r0 != 0xFFFFFFFFu) {
            unsigned bkt = r0 >> 16;
            unsigned r = atomicAdd(&cnt[bkt], 1u);
            sorted[r] = (unsigned short)(r0 & 0xFFFFu);
        }
    }
    __syncthreads();
    // phase 4: linear coalesced flush into this block's own seg region
    unsigned short* segb = seg + (size_t)bid * (size_t)chunk;
    for (int i = j; i < m; i += RTHR) segb[i] = sorted[i];
}

// Cooperative scan, 1024 blocks x 256 thr (R9-R17 core, byte-identical
// barrier/LIF machinery). R22: run-table read is contiguous (transposed
// mat); hist-build is wave-cooperative -- 16-lane subgroups per run
// (replaces the 30-deep serial per-thread load chain of R21).
__global__ __launch_bounds__(STHR, 4) void scan_new(float* __restrict__ out,
                                                    const unsigned short* __restrict__ seg,
                                                    const unsigned* __restrict__ mat,
                                                    int n) {
#pragma clang fp contract(off)
    const float decay = (float)0.9048374180359595;  // float32(exp(-1/10))
    const int tid = threadIdx.x;
    const int lane = tid & 63;
    const int b = blockIdx.x;
    const int pix0 = b * PIXB;

    __shared__ alignas(16) unsigned lds_hist[HIST_W];
    __shared__ unsigned runw[RBLK];
    __shared__ unsigned lds_arr[T_TOTAL];
    __shared__ unsigned lds_tot[T_TOTAL];

    for (int i = tid; i < HIST_W; i += STHR) lds_hist[i] = 0u;
    for (int r = tid; r < RBLK; r += STHR) runw[r] = mat[b * RBLK + r];
    if (tid < T_TOTAL) { lds_arr[tid] = 0u; lds_tot[tid] = 0u; }
    __syncthreads();

    {
        const int chunk = (((n + RBLK - 1) / RBLK) + 3) & ~3;
        const int sg = tid >> 4;         // 16-lane subgroup id, 0..15 per wave
        const int sl = tid & 15;
        for (int r = sg; r < RBLK; r += (STHR >> 4)) {
            unsigned w = runw[r];
            unsigned c = w & 0xFFFFu;
            const unsigned short* sp = seg + (size_t)r * (size_t)chunk + (w >> 16);
            for (unsigned k = sl; k < c; k += 16) {
                unsigned lb = sp[k];
                atomicAdd(&lds_hist[lb >> 1], 1u << ((lb & 1u) << 4));
            }
        }
    }
    __syncthreads();

    const bool has1 = tid < (NGROUP4 - STHR);
    float4 mem0 = make_float4(0.f, 0.f, 0.f, 0.f);
    float4 mem1 = make_float4(0.f, 0.f, 0.f, 0.f);
    float thr = 1.0f;

    float4 f0, f1;
    {
        uint2 w01 = *(const uint2*)&lds_hist[tid << 1];
        f0 = make_float4((float)(w01.x & 0xFFFFu), (float)(w01.x >> 16),
                         (float)(w01.y & 0xFFFFu), (float)(w01.y >> 16));
        if (has1) {
            uint2 v = *(const uint2*)&lds_hist[(tid + STHR) << 1];
            f1 = make_float4((float)(v.x & 0xFFFFu), (float)(v.x >> 16),
                             (float)(v.y & 0xFFFFu), (float)(v.y >> 16));
        } else f1 = make_float4(0.f, 0.f, 0.f, 0.f);
    }

    for (int s = 0;; ++s) {
        float* ob = out + (size_t)s * FRAME + pix0;
        int cnt = 0;

        {
            float4 m, spk;
            m.x = mem0.x + f0.x;
            m.y = mem0.y + f0.y;
            m.z = mem0.z + f0.z;
            m.w = mem0.w + f0.w;
            spk.x = (m.x >= thr) ? 1.0f : 0.0f;
            spk.y = (m.y >= thr) ? 1.0f : 0.0f;
            spk.z = (m.z >= thr) ? 1.0f : 0.0f;
            spk.w = (m.w >= thr) ? 1.0f : 0.0f;
            ((float4*)ob)[tid] = spk;
            mem0.x = m.x - spk.x * thr;
            mem0.y = m.y - spk.y * thr;
            mem0.z = m.z - spk.z * thr;
            mem0.w = m.w - spk.w * thr;
            cnt += (int)spk.x + (int)spk.y + (int)spk.z + (int)spk.w;
        }
        if (has1) {
            int g = tid + STHR;
            float4 m, spk;
            m.x = mem1.x + f1.x;
            m.y = mem1.y + f1.y;
            m.z = mem1.z + f1.z;
            m.w = mem1.w + f1.w;
            spk.x = (m.x >= thr) ? 1.0f : 0.0f;
            spk.y = (m.y >= thr) ? 1.0f : 0.0f;
            spk.z = (m.z >= thr) ? 1.0f : 0.0f;
            spk.w = (m.w >= thr) ? 1.0f : 0.0f;
            ((float4*)ob)[g] = spk;
            mem1.x = m.x - spk.x * thr;
            mem1.y = m.y - spk.y * thr;
            mem1.z = m.z - spk.z * thr;
            mem1.w = m.w - spk.w * thr;
            cnt += (int)spk.x + (int)spk.y + (int)spk.z + (int)spk.w;
        }

        if (s == T_TOTAL - 1) break;

        for (int off = 32; off > 0; off >>= 1) cnt += __shfl_down(cnt, off, 64);

        // ---- arrive phase (leader only; no polling yet) ----
        bool last = false;
        const int g1 = b >> 4;
        if (lane == 0) {
            unsigned old = __hip_atomic_fetch_add(&lds_arr[s],
                               (unsigned)cnt + (1u << 16),
                               __ATOMIC_RELAXED, __HIP_MEMORY_SCOPE_WORKGROUP);
            if ((old >> 16) == SWPB - 1) {
                last = true;
                unsigned bc = (old + (unsigned)cnt) & 0xFFFFu;
                unsigned long long a1 = __hip_atomic_fetch_add(
                    &g_n1[s][g1][0], (unsigned long long)bc + ARRIVE64,
                    __ATOMIC_RELAXED, __HIP_MEMORY_SCOPE_AGENT);
                if ((unsigned)(a1 >> 32) == 15u) {
                    unsigned c1 = (unsigned)a1 + bc;
                    const int g2 = g1 >> 4;
                    unsigned long long a2 = __hip_atomic_fetch_add(
                        &g_n2[s][g2][0], (unsigned long long)c1 + ARRIVE64,
                        __ATOMIC_RELAXED, __HIP_MEMORY_SCOPE_AGENT);
                    if ((unsigned)(a2 >> 32) == 15u) {
                        unsigned c2 = (unsigned)a2 + c1;
                        unsigned long long a3 = __hip_atomic_fetch_add(
                            &g_n3[s][0], (unsigned long long)c2 + ARRIVE64,
                            __ATOMIC_RELAXED, __HIP_MEMORY_SCOPE_AGENT);
                        if ((unsigned)(a3 >> 32) == 3u) {
                            unsigned tot = (unsigned)a3 + c2;
                            for (int g = 0; g < 64; ++g)
                                __hip_atomic_store(&g_relg[s][g][0], tot + 1u,
                                    __ATOMIC_RELAXED, __HIP_MEMORY_SCOPE_AGENT);
                        }
                    }
                }
            }
        }

        // ---- prefetch next frame + pre-decay, under the barrier shadow ----
        {
            const int sn = s + 1;
            if (sn < T_EVT) {
                uint2 w01 = *(const uint2*)&lds_hist[sn * 900 + (tid << 1)];
                f0 = make_float4((float)(w01.x & 0xFFFFu), (float)(w01.x >> 16),
                                 (float)(w01.y & 0xFFFFu), (float)(w01.y >> 16));
                if (has1) {
                    uint2 v = *(const uint2*)&lds_hist[sn * 900 + ((tid + STHR) << 1)];
                    f1 = make_float4((float)(v.x & 0xFFFFu), (float)(v.x >> 16),
                                     (float)(v.y & 0xFFFFu), (float)(v.y >> 16));
                }
            } else {
                f0 = make_float4(0.f, 0.f, 0.f, 0.f);
                f1 = make_float4(0.f, 0.f, 0.f, 0.f);
            }
            mem0.x = mem0.x * decay; mem0.y = mem0.y * decay;
            mem0.z = mem0.z * decay; mem0.w = mem0.w * decay;
            mem1.x = mem1.x * decay; mem1.y = mem1.y * decay;
            mem1.z = mem1.z * decay; mem1.w = mem1.w * decay;
        }
        __builtin_amdgcn_sched_barrier(0);   // keep prefetch before the poll

        // ---- poll phase ----
        unsigned total = 0u;
        if (lane == 0) {
            unsigned f;
            if (last) {
                do {
                    __builtin_amdgcn_s_sleep(1);
                    f = __hip_atomic_load(&g_relg[s][g1][0], __ATOMIC_RELAXED,
                                          __HIP_MEMORY_SCOPE_AGENT);
                } while (f == 0u);
                total = f - 1u;
                __hip_atomic_store(&lds_tot[s], f,
                                   __ATOMIC_RELAXED, __HIP_MEMORY_SCOPE_WORKGROUP);
            } else {
                unsigned f2;
                do {
                    __builtin_amdgcn_s_sleep(1);
                    f2 = __hip_atomic_load(&lds_tot[s], __ATOMIC_RELAXED,
                                           __HIP_MEMORY_SCOPE_WORKGROUP);
                } while (f2 == 0u);
                total = f2 - 1u;
            }
        }
        total = (unsigned)__shfl((int)total, 0, 64);
        float rate = (float)total / 1843200.0f;
        thr = thr + 0.1f * (rate - 0.1f);
        thr = fminf(fmaxf(thr, 0.1f), 10.0f);
    }
}

// ======================= old (fallback) path =======================
__global__ void scatter_kernel(const int* __restrict__ x, const int* __restrict__ y,
                               const int* __restrict__ p, const float* __restrict__ t,
                               unsigned* __restrict__ hist32, int n) {
    int i = blockIdx.x * blockDim.x + threadIdx.x;
    if (i >= n) return;
    float tmin = key2f(g_minkey);
    float tmax = key2f(g_maxkey);
    int ti = event_bin_t(t[i], tmin, tmax);
    int pix = event_pixel(x[i], y[i], p[i]);
    size_t bidx = (size_t)ti * FRAME + pix;
    atomicAdd(hist32 + (bidx >> 1), 1u << ((bidx & 1) << 4));
}

__global__ __launch_bounds__(ONTHR) void scan_old(float* __restrict__ out) {
#pragma clang fp contract(off)
    const float decay = (float)0.9048374180359595;
    const int gtid = blockIdx.x * ONTHR + threadIdx.x;
    const int lane = threadIdx.x & 63;
    const uint2 uz2 = make_uint2(0u, 0u);
    float4 mem0 = make_float4(0.f, 0.f, 0.f, 0.f);
    float4 mem1 = make_float4(0.f, 0.f, 0.f, 0.f);
    const bool has1 = (gtid + ONT) < FRAME4;
    float thr = 1.0f;
    const uint2* hist2 = (const uint2*)(out + (size_t)T_EVT * FRAME);
    __shared__ unsigned lds_arr[T_TOTAL];
    __shared__ unsigned lds_tot[T_TOTAL];
    if (threadIdx.x < T_TOTAL) { lds_arr[threadIdx.x] = 0u; lds_tot[threadIdx.x] = 0u; }
    __syncthreads();
    uint2 u0 = hist2[gtid];
    uint2 u1 = has1 ? hist2[gtid + ONT] : uz2;
    for (int s = 0; s < T_TOTAL; ++s) {
        float4* o4 = (float4*)(out + (size_t)s * FRAME);
        int cnt = 0;
        {
            float4 m, spk;
            m.x = mem0.x * decay; m.x = m.x + (float)(u0.x & 0xFFFFu);
            m.y = mem0.y * decay; m.y = m.y + (float)(u0.x >> 16);
            m.z = mem0.z * decay; m.z = m.z + (float)(u0.y & 0xFFFFu);
            m.w = mem0.w * decay; m.w = m.w + (float)(u0.y >> 16);
            spk.x = (m.x >= thr) ? 1.0f : 0.0f;
            spk.y = (m.y >= thr) ? 1.0f : 0.0f;
            spk.z = (m.z >= thr) ? 1.0f : 0.0f;
            spk.w = (m.w >= thr) ? 1.0f : 0.0f;
            o4[gtid] = spk;
            mem0.x = m.x - spk.x * thr; mem0.y = m.y - spk.y * thr;
            mem0.z = m.z - spk.z * thr; mem0.w = m.w - spk.w * thr;
            cnt += (int)spk.x + (int)spk.y + (int)spk.z + (int)spk.w;
        }
        if (has1) {
            float4 m, spk;
            m.x = mem1.x * decay; m.x = m.x + (float)(u1.x & 0xFFFFu);
            m.y = mem1.y * decay; m.y = m.y + (float)(u1.x >> 16);
            m.z = mem1.z * decay; m.z = m.z + (float)(u1.y & 0xFFFFu);
            m.w = mem1.w * decay; m.w = m.w + (float)(u1.y >> 16);
            spk.x = (m.x >= thr) ? 1.0f : 0.0f;
            spk.y = (m.y >= thr) ? 1.0f : 0.0f;
            spk.z = (m.z >= thr) ? 1.0f : 0.0f;
            spk.w = (m.w >= thr) ? 1.0f : 0.0f;
            o4[gtid + ONT] = spk;
            mem1.x = m.x - spk.x * thr; mem1.y = m.y - spk.y * thr;
            mem1.z = m.z - spk.z * thr; mem1.w = m.w - spk.w * thr;
            cnt += (int)spk.x + (int)spk.y + (int)spk.z + (int)spk.w;
        }
        if (s + 1 < T_EVT) {
            const uint2* hn = hist2 + (size_t)(s + 1) * FRAME4;
            u0 = hn[gtid];
            u1 = has1 ? hn[gtid + ONT] : uz2;
        } else { u0 = uz2; u1 = uz2; }
        if (s == T_TOTAL - 1) break;
        for (int off = 32; off > 0; off >>= 1) cnt += __shfl_down(cnt, off, 64);
        unsigned total = 0u;
        if (lane == 0) {
            unsigned old = __hip_atomic_fetch_add(&lds_arr[s],
                               (unsigned)cnt + (1u << 16),
                               __ATOMIC_RELAXED, __HIP_MEMORY_SCOPE_WORKGROUP);
            if ((old >> 16) == ONWPB - 1) {
                unsigned bc = (old + (unsigned)cnt) & 0xFFFFu;
                const int gid = blockIdx.x >> 4;
                unsigned long long gold = __hip_atomic_fetch_add(
                    &g_grp[s][gid][0], (unsigned long long)bc + ARRIVE64,
                    __ATOMIC_RELAXED, __HIP_MEMORY_SCOPE_AGENT);
                if ((unsigned)(gold >> 32) == 15u) {
                    unsigned gc = (unsigned)gold + bc;
                    unsigned long long told = __hip_atomic_fetch_add(
                        &g_top[s][0], (unsigned long long)gc + ARRIVE64,
                        __ATOMIC_RELAXED, __HIP_MEMORY_SCOPE_AGENT);
                    if ((unsigned)(told >> 32) == 15u) {
                        unsigned tot = (unsigned)told + gc;
                        __hip_atomic_store(&g_rel[s][0], tot + 1u,
                                           __ATOMIC_RELAXED, __HIP_MEMORY_SCOPE_AGENT);
                    }
                }
                unsigned f;
                do {
                    __builtin_amdgcn_s_sleep(1);
                    f = __hip_atomic_load(&g_rel[s][0], __ATOMIC_RELAXED,
                                          __HIP_MEMORY_SCOPE_AGENT);
                } while (f == 0u);
                total = f - 1u;
                __hip_atomic_store(&lds_tot[s], f,
                                   __ATOMIC_RELAXED, __HIP_MEMORY_SCOPE_WORKGROUP);
            } else {
                unsigned f;
                do {
                    __builtin_amdgcn_s_sleep(1);
                    f = __hip_atomic_load(&lds_tot[s], __ATOMIC_RELAXED,
                                          __HIP_MEMORY_SCOPE_WORKGROUP);
                } while (f == 0u);
                total = f - 1u;
            }
        }
        total = (unsigned)__shfl((int)total, 0, 64);
        float rate = (float)total / 1843200.0f;
        thr = thr + 0.1f * (rate - 0.1f);
        thr = fminf(fmaxf(thr, 0.1f), 10.0f);
    }
}

extern "C" void kernel_launch(void* const* d_in, const int* in_sizes, int n_in,
                              void* d_out, int out_size, void* d_ws, size_t ws_size,
                              hipStream_t stream) {
    const int*   x = (const int*)d_in[0];
    const int*   y = (const int*)d_in[1];
    const int*   p = (const int*)d_in[2];
    const float* t = (const float*)d_in[3];
    float* out = (float*)d_out;
    const int n = in_sizes[0];

    const int chunk = (((n + RBLK - 1) / RBLK) + 3) & ~3;
    if (d_ws != nullptr && ws_size >= WS_NEED(chunk) && chunk <= MAXM && n >= 4) {
        unsigned* mat = (unsigned*)((char*)d_ws + MAT_OFF);
        unsigned short* seg = (unsigned short*)((char*)d_ws + KEY_OFF);

        minmax_ws_kernel<<<MMBLK, MMTHR, 0, stream>>>(t, n);
        passAB_kernel<<<RBLK, RTHR, 0, stream>>>(x, y, p, t, mat, seg, n);

        dim3 g(SBLK), b(STHR);
        void* args[] = { (void*)&out, (void*)&seg, (void*)&mat, (void*)&n };
        hipLaunchCooperativeKernel((void*)scan_new, g, b, args, 0, stream);
    } else {
        init_kernel<<<64, 256, 0, stream>>>();
        unsigned* hist32 = (unsigned*)(out + (size_t)T_EVT * FRAME);
        minmax_zero_kernel<<<1024, 256, 0, stream>>>(t, n, (uint4*)hist32);
        scatter_kernel<<<(n + 255) / 256, 256, 0, stream>>>(x, y, p, t, hist32, n);
        dim3 g(ONBLK), b(ONTHR);
        void* args[] = { (void*)&out };
        hipLaunchCooperativeKernel((void*)scan_old, g, b, args, 0, stream);
    }
}